// Round 1
// baseline (3966.201 us; speedup 1.0000x reference)
//
#include <hip/hip_runtime.h>
#include <hip/hip_bf16.h>
#include <math.h>

// Problem constants (from reference)
#define BB 64
#define LL 512
#define CC 256
#define HH 8
#define DHH 32
#define NN (BB * LL)

// ---------------------------------------------------------------------------
// K1: scorer. scores[tok] = relu(x@Ws1^T + bs1) @ Ws2^T + bs2
// 8 tokens per block, 256 threads (thread t = hidden unit t).
// ---------------------------------------------------------------------------
__global__ __launch_bounds__(256) void k_scorer(
    const float* __restrict__ x, const float* __restrict__ Ws1,
    const float* __restrict__ bs1, const float* __restrict__ Ws2,
    const float* __restrict__ bs2, float* __restrict__ scores) {
  __shared__ float xs[8][CC];
  __shared__ float wred[8][4];
  int t = threadIdx.x;
  int lane = t & 63, wid = t >> 6;
  int tok0 = blockIdx.x * 8;
  for (int i = 0; i < 8; ++i) xs[i][t] = x[(size_t)(tok0 + i) * CC + t];
  __syncthreads();
  float acc[8];
#pragma unroll
  for (int i = 0; i < 8; ++i) acc[i] = 0.f;
  const float* wrow = Ws1 + (size_t)t * CC;
  for (int j = 0; j < CC; j += 4) {
    float4 w = *(const float4*)(wrow + j);
#pragma unroll
    for (int i = 0; i < 8; ++i) {
      acc[i] += xs[i][j] * w.x + xs[i][j + 1] * w.y + xs[i][j + 2] * w.z +
                xs[i][j + 3] * w.w;
    }
  }
  float b1 = bs1[t], w2 = Ws2[t];
#pragma unroll
  for (int i = 0; i < 8; ++i) {
    float v = fmaxf(acc[i] + b1, 0.f) * w2;
    for (int o = 32; o > 0; o >>= 1) v += __shfl_down(v, o);
    if (lane == 0) wred[i][wid] = v;
  }
  __syncthreads();
  if (t < 8)
    scores[tok0 + t] = wred[t][0] + wred[t][1] + wred[t][2] + wred[t][3] + bs2[0];
}

// ---------------------------------------------------------------------------
// K2a: k_per[b] = clip(ceil(ratio*L),1,512); k_max = max_b k_per
// ---------------------------------------------------------------------------
__global__ __launch_bounds__(64) void k_kper(const float* __restrict__ ratio,
                                             int* __restrict__ k_per,
                                             int* __restrict__ k_maxp) {
  int t = threadIdx.x;
  int kp = (int)ceilf(ratio[t] * (float)LL);
  kp = min(max(kp, 1), LL);
  k_per[t] = kp;
  int m = kp;
  for (int o = 32; o > 0; o >>= 1) m = max(m, __shfl_down(m, o));
  if (t == 0) *k_maxp = m;
}

// ---------------------------------------------------------------------------
// K2: z[b,l] = scores[b,l] - logsumexp_l(scores[b,:]) + gumbel[b,l]  (in place)
// one block per batch, 256 threads (2 elems each)
// ---------------------------------------------------------------------------
__global__ __launch_bounds__(256) void k_lsg(float* __restrict__ z,
                                             const float* __restrict__ gumbel) {
  int b = blockIdx.x, t = threadIdx.x;
  int lane = t & 63, wid = t >> 6;
  __shared__ float wred[4];
  float v0 = z[b * LL + t], v1 = z[b * LL + 256 + t];
  float m = fmaxf(v0, v1);
  for (int o = 32; o > 0; o >>= 1) m = fmaxf(m, __shfl_down(m, o));
  if (lane == 0) wred[wid] = m;
  __syncthreads();
  m = fmaxf(fmaxf(wred[0], wred[1]), fmaxf(wred[2], wred[3]));
  __syncthreads();
  float e = expf(v0 - m) + expf(v1 - m);
  for (int o = 32; o > 0; o >>= 1) e += __shfl_down(e, o);
  if (lane == 0) wred[wid] = e;
  __syncthreads();
  float lse = m + logf(wred[0] + wred[1] + wred[2] + wred[3]);
  z[b * LL + t] = v0 - lse + gumbel[b * LL + t];
  z[b * LL + 256 + t] = v1 - lse + gumbel[b * LL + 256 + t];
}

// ---------------------------------------------------------------------------
// K3: selection. codes[b,l]: kept -> compact row (0..kp-1); pad -> kp; else -1
// row2l[b,r] = node position of compact row r. One block/batch, 512 threads.
// ---------------------------------------------------------------------------
__global__ __launch_bounds__(512) void k_select(
    const float* __restrict__ z, const int* __restrict__ k_per,
    const int* __restrict__ k_maxp, int* __restrict__ codes,
    int* __restrict__ row2l) {
  __shared__ float zs[LL];
  __shared__ int sel[LL];
  int b = blockIdx.x, l = threadIdx.x;
  int kp = k_per[b], km = *k_maxp;
  float zl = z[b * LL + l];
  zs[l] = zl;
  __syncthreads();
  int rank = 0;
  for (int j = 0; j < LL; ++j) {
    float zj = zs[j];
    rank += (zj > zl) || (zj == zl && j < l);
  }
  int s = (rank < km) ? 1 : 0;
  sel[l] = s;
  __syncthreads();
  int ps = 0;
  for (int j = 0; j < l; ++j) ps += sel[j];
  int kept = s && (ps < kp);
  int keptPrefix = min(ps, kp);
  int code;
  if (kept)
    code = ps;                       // compact row index
  else if ((l - keptPrefix) < (km - kp))
    code = kp;                       // pad-scatter position -> pad row kp
  else
    code = -1;                       // stays zero
  codes[b * LL + l] = code;
  if (kept) row2l[b * LL + ps] = l;
}

// ---------------------------------------------------------------------------
// K4: qkv in-proj for compact rows 0..kp (row kp = pad row with zero input,
// only when kp<512). 8 rows per block; thread t = channel t.
// ---------------------------------------------------------------------------
__global__ __launch_bounds__(256) void k_qkv(
    const float* __restrict__ x, const int* __restrict__ row2l,
    const int* __restrict__ k_per, const float* __restrict__ Win,
    const float* __restrict__ b_in, float* __restrict__ qb,
    float* __restrict__ kb, float* __restrict__ vb) {
  int b = blockIdx.y;
  int r0 = blockIdx.x * 8;
  int t = threadIdx.x;
  int kp = k_per[b];
  int rows = (kp < LL) ? kp + 1 : LL;
  if (r0 >= rows) return;
  __shared__ float xs[8][CC];
  int nv = min(8, rows - r0);
  for (int i = 0; i < nv; ++i) {
    int r = r0 + i;
    if (r < kp) {
      int l = row2l[b * LL + r];
      xs[i][t] = x[((size_t)b * LL + l) * CC + t];
    } else {
      xs[i][t] = 0.f;  // pad row: zero input -> qkv = b_in
    }
  }
  __syncthreads();
  float aq[8], ak[8], av[8];
#pragma unroll
  for (int i = 0; i < 8; ++i) { aq[i] = 0.f; ak[i] = 0.f; av[i] = 0.f; }
  const float* wq = Win + (size_t)t * CC;
  const float* wk = Win + (size_t)(CC + t) * CC;
  const float* wv = Win + (size_t)(2 * CC + t) * CC;
  for (int j = 0; j < CC; j += 4) {
    float4 q4 = *(const float4*)(wq + j);
    float4 k4 = *(const float4*)(wk + j);
    float4 v4 = *(const float4*)(wv + j);
#pragma unroll
    for (int i = 0; i < 8; ++i) {
      float x0 = xs[i][j], x1 = xs[i][j + 1], x2 = xs[i][j + 2], x3 = xs[i][j + 3];
      aq[i] += x0 * q4.x + x1 * q4.y + x2 * q4.z + x3 * q4.w;
      ak[i] += x0 * k4.x + x1 * k4.y + x2 * k4.z + x3 * k4.w;
      av[i] += x0 * v4.x + x1 * v4.y + x2 * v4.z + x3 * v4.w;
    }
  }
  float bq = b_in[t], bk2 = b_in[CC + t], bv2 = b_in[2 * CC + t];
  for (int i = 0; i < nv; ++i) {
    size_t o = ((size_t)b * LL + r0 + i) * CC + t;
    qb[o] = aq[i] + bq;
    kb[o] = ak[i] + bk2;
    vb[o] = av[i] + bv2;
  }
}

// ---------------------------------------------------------------------------
// K6: attention, one wave per (q-row, head, batch). Writes output over q.
// Keys are rows < kp (mask). Row kp (pad query) handled like any q row.
// ---------------------------------------------------------------------------
__global__ __launch_bounds__(64) void k_attn(float* __restrict__ qb,
                                             const float* __restrict__ kb,
                                             const float* __restrict__ vb,
                                             const int* __restrict__ k_per) {
  int q = blockIdx.x, h = blockIdx.y, b = blockIdx.z;
  int kp = k_per[b];
  int rows = (kp < LL) ? kp + 1 : LL;
  if (q >= rows) return;
  int t = threadIdx.x;
  __shared__ float qs[DHH];
  __shared__ float sc[LL];
  size_t base = ((size_t)b * LL) * CC + h * DHH;
  if (t < DHH) qs[t] = qb[base + (size_t)q * CC + t];
  __syncthreads();
  const float scale = 0.17677669529663687f;  // 1/sqrt(32)
  for (int key = t; key < kp; key += 64) {
    const float* kr = kb + base + (size_t)key * CC;
    float d = 0.f;
#pragma unroll
    for (int j = 0; j < DHH; ++j) d += qs[j] * kr[j];
    sc[key] = d * scale;
  }
  __syncthreads();
  float lmax = -INFINITY;
  for (int key = t; key < kp; key += 64) lmax = fmaxf(lmax, sc[key]);
  for (int o = 32; o > 0; o >>= 1) lmax = fmaxf(lmax, __shfl_down(lmax, o));
  lmax = __shfl(lmax, 0);
  float lsum = 0.f;
  for (int key = t; key < kp; key += 64) {
    float e = expf(sc[key] - lmax);
    sc[key] = e;
    lsum += e;
  }
  for (int o = 32; o > 0; o >>= 1) lsum += __shfl_down(lsum, o);
  lsum = __shfl(lsum, 0);
  __syncthreads();
  int d = t & 31, half = t >> 5;
  float acc = 0.f;
  for (int key = half; key < kp; key += 2)
    acc += sc[key] * vb[base + (size_t)key * CC + d];
  acc += __shfl_down(acc, 32);
  if (t < 32) qb[base + (size_t)q * CC + d] = acc / lsum;
}

// ---------------------------------------------------------------------------
// K7: out-proj + scatter + residual + ratio scale. 8 node positions / block.
// code>=0 -> compact row (incl pad row kp); code<0 -> zero.
// ---------------------------------------------------------------------------
__global__ __launch_bounds__(256) void k_outproj(
    const float* __restrict__ attnO, const int* __restrict__ codes,
    const float* __restrict__ Wout, const float* __restrict__ bout,
    const float* __restrict__ x, const float* __restrict__ ratio,
    float* __restrict__ out) {
  int b = blockIdx.y;
  int l0 = blockIdx.x * 8;
  int t = threadIdx.x;
  __shared__ float As[8][CC];
  __shared__ int cd[8];
  if (t < 8) cd[t] = codes[b * LL + l0 + t];
  __syncthreads();
  for (int i = 0; i < 8; ++i) {
    int c = cd[i];
    if (c >= 0) As[i][t] = attnO[((size_t)b * LL + c) * CC + t];
  }
  __syncthreads();
  float acc[8];
#pragma unroll
  for (int i = 0; i < 8; ++i) acc[i] = 0.f;
  const float* w = Wout + (size_t)t * CC;
  for (int j = 0; j < CC; j += 4) {
    float4 w4 = *(const float4*)(w + j);
#pragma unroll
    for (int i = 0; i < 8; ++i) {
      acc[i] += As[i][j] * w4.x + As[i][j + 1] * w4.y + As[i][j + 2] * w4.z +
                As[i][j + 3] * w4.w;
    }
  }
  float bo = bout[t], rt = ratio[b];
  for (int i = 0; i < 8; ++i) {
    int c = cd[i];
    float y = (c >= 0) ? (acc[i] + bo) : 0.f;
    size_t o = ((size_t)b * LL + l0 + i) * CC + t;
    out[o] = (y + x[o]) * rt;
  }
}

// ---------------------------------------------------------------------------
// K8: MLP residual: out += relu(out@Wm1^T + bm1)@Wm2^T + bm2. 8 tokens/block.
// ---------------------------------------------------------------------------
__global__ __launch_bounds__(256) void k_mlp(const float* __restrict__ Wm1,
                                             const float* __restrict__ bm1,
                                             const float* __restrict__ Wm2,
                                             const float* __restrict__ bm2,
                                             float* __restrict__ out) {
  __shared__ float hs[8][CC];
  __shared__ float ms[8][2 * CC];
  int tok0 = blockIdx.x * 8;
  int t = threadIdx.x;
  for (int i = 0; i < 8; ++i) hs[i][t] = out[(size_t)(tok0 + i) * CC + t];
  __syncthreads();
  float a0[8], a1[8];
#pragma unroll
  for (int i = 0; i < 8; ++i) { a0[i] = 0.f; a1[i] = 0.f; }
  const float* w0 = Wm1 + (size_t)t * CC;
  const float* w1 = Wm1 + (size_t)(CC + t) * CC;
  for (int j = 0; j < CC; j += 4) {
    float4 u0 = *(const float4*)(w0 + j);
    float4 u1 = *(const float4*)(w1 + j);
#pragma unroll
    for (int i = 0; i < 8; ++i) {
      float h0 = hs[i][j], h1 = hs[i][j + 1], h2 = hs[i][j + 2], h3 = hs[i][j + 3];
      a0[i] += h0 * u0.x + h1 * u0.y + h2 * u0.z + h3 * u0.w;
      a1[i] += h0 * u1.x + h1 * u1.y + h2 * u1.z + h3 * u1.w;
    }
  }
  float c0 = bm1[t], c1 = bm1[CC + t];
  for (int i = 0; i < 8; ++i) {
    ms[i][t] = fmaxf(a0[i] + c0, 0.f);
    ms[i][CC + t] = fmaxf(a1[i] + c1, 0.f);
  }
  __syncthreads();
  float a2[8];
#pragma unroll
  for (int i = 0; i < 8; ++i) a2[i] = 0.f;
  const float* w2 = Wm2 + (size_t)t * (2 * CC);
  for (int j = 0; j < 2 * CC; j += 4) {
    float4 w4 = *(const float4*)(w2 + j);
#pragma unroll
    for (int i = 0; i < 8; ++i) {
      a2[i] += ms[i][j] * w4.x + ms[i][j + 1] * w4.y + ms[i][j + 2] * w4.z +
               ms[i][j + 3] * w4.w;
    }
  }
  float c2 = bm2[t];
  for (int i = 0; i < 8; ++i)
    out[(size_t)(tok0 + i) * CC + t] = hs[i][t] + a2[i] + c2;
}

// ---------------------------------------------------------------------------
extern "C" void kernel_launch(void* const* d_in, const int* in_sizes, int n_in,
                              void* d_out, int out_size, void* d_ws,
                              size_t ws_size, hipStream_t stream) {
  (void)in_sizes; (void)n_in; (void)out_size; (void)ws_size;
  const float* x     = (const float*)d_in[0];
  // d_in[1] edge_index (unused, conv=None); d_in[2] batch (b = tok/L)
  const float* ratio = (const float*)d_in[3];
  const float* gum   = (const float*)d_in[4];
  const float* Ws1   = (const float*)d_in[5];
  const float* bs1   = (const float*)d_in[6];
  const float* Ws2   = (const float*)d_in[7];
  const float* bs2   = (const float*)d_in[8];
  const float* Win   = (const float*)d_in[9];
  const float* b_in  = (const float*)d_in[10];
  const float* Wout  = (const float*)d_in[11];
  const float* bout  = (const float*)d_in[12];
  const float* Wm1   = (const float*)d_in[13];
  const float* bm1   = (const float*)d_in[14];
  const float* Wm2   = (const float*)d_in[15];
  const float* bm2   = (const float*)d_in[16];
  float* out = (float*)d_out;

  // workspace layout (floats/ints, all 4-byte)
  float* z    = (float*)d_ws;            // N
  int* k_per  = (int*)(z + NN);          // 64 (+64 reserve)
  int* k_maxp = k_per + 64;
  int* codes  = k_per + 128;             // N
  int* row2l  = codes + NN;              // N
  float* qb   = (float*)(row2l + NN);    // B*L*C
  float* kb   = qb + (size_t)BB * LL * CC;
  float* vb   = kb + (size_t)BB * LL * CC;

  k_scorer<<<NN / 8, 256, 0, stream>>>(x, Ws1, bs1, Ws2, bs2, z);
  k_kper<<<1, 64, 0, stream>>>(ratio, k_per, k_maxp);
  k_lsg<<<BB, 256, 0, stream>>>(z, gum);
  k_select<<<BB, 512, 0, stream>>>(z, k_per, k_maxp, codes, row2l);
  k_qkv<<<dim3(64, BB), 256, 0, stream>>>(x, row2l, k_per, Win, b_in, qb, kb, vb);
  k_attn<<<dim3(LL, HH, BB), 64, 0, stream>>>(qb, kb, vb, k_per);
  k_outproj<<<dim3(64, BB), 256, 0, stream>>>(qb, codes, Wout, bout, x, ratio, out);
  k_mlp<<<NN / 8, 256, 0, stream>>>(Wm1, bm1, Wm2, bm2, out);
}

// Round 2
// 2279.308 us; speedup vs baseline: 1.7401x; 1.7401x over previous
//
#include <hip/hip_runtime.h>
#include <hip/hip_bf16.h>
#include <math.h>

// Problem constants (from reference)
#define BB 64
#define LL 512
#define CC 256
#define HH 8
#define DHH 32
#define NN (BB * LL)

// ---------------------------------------------------------------------------
// K1: scorer. scores[tok] = relu(x@Ws1^T + bs1) @ Ws2^T + bs2
// 8 tokens per block, 256 threads (thread t = hidden unit t).
// ---------------------------------------------------------------------------
__global__ __launch_bounds__(256) void k_scorer(
    const float* __restrict__ x, const float* __restrict__ Ws1,
    const float* __restrict__ bs1, const float* __restrict__ Ws2,
    const float* __restrict__ bs2, float* __restrict__ scores) {
  __shared__ float xs[8][CC];
  __shared__ float wred[8][4];
  int t = threadIdx.x;
  int lane = t & 63, wid = t >> 6;
  int tok0 = blockIdx.x * 8;
  for (int i = 0; i < 8; ++i) xs[i][t] = x[(size_t)(tok0 + i) * CC + t];
  __syncthreads();
  float acc[8];
#pragma unroll
  for (int i = 0; i < 8; ++i) acc[i] = 0.f;
  const float* wrow = Ws1 + (size_t)t * CC;
  for (int j = 0; j < CC; j += 4) {
    float4 w = *(const float4*)(wrow + j);
#pragma unroll
    for (int i = 0; i < 8; ++i) {
      acc[i] += xs[i][j] * w.x + xs[i][j + 1] * w.y + xs[i][j + 2] * w.z +
                xs[i][j + 3] * w.w;
    }
  }
  float b1 = bs1[t], w2 = Ws2[t];
#pragma unroll
  for (int i = 0; i < 8; ++i) {
    float v = fmaxf(acc[i] + b1, 0.f) * w2;
    for (int o = 32; o > 0; o >>= 1) v += __shfl_down(v, o);
    if (lane == 0) wred[i][wid] = v;
  }
  __syncthreads();
  if (t < 8)
    scores[tok0 + t] = wred[t][0] + wred[t][1] + wred[t][2] + wred[t][3] + bs2[0];
}

// ---------------------------------------------------------------------------
// K2a: k_per[b] = clip(ceil(ratio*L),1,512); k_max = max_b k_per
// ---------------------------------------------------------------------------
__global__ __launch_bounds__(64) void k_kper(const float* __restrict__ ratio,
                                             int* __restrict__ k_per,
                                             int* __restrict__ k_maxp) {
  int t = threadIdx.x;
  int kp = (int)ceilf(ratio[t] * (float)LL);
  kp = min(max(kp, 1), LL);
  k_per[t] = kp;
  int m = kp;
  for (int o = 32; o > 0; o >>= 1) m = max(m, __shfl_down(m, o));
  if (t == 0) *k_maxp = m;
}

// ---------------------------------------------------------------------------
// K2: z[b,l] = scores[b,l] - logsumexp_l(scores[b,:]) + gumbel[b,l]  (in place)
// ---------------------------------------------------------------------------
__global__ __launch_bounds__(256) void k_lsg(float* __restrict__ z,
                                             const float* __restrict__ gumbel) {
  int b = blockIdx.x, t = threadIdx.x;
  int lane = t & 63, wid = t >> 6;
  __shared__ float wred[4];
  float v0 = z[b * LL + t], v1 = z[b * LL + 256 + t];
  float m = fmaxf(v0, v1);
  for (int o = 32; o > 0; o >>= 1) m = fmaxf(m, __shfl_down(m, o));
  if (lane == 0) wred[wid] = m;
  __syncthreads();
  m = fmaxf(fmaxf(wred[0], wred[1]), fmaxf(wred[2], wred[3]));
  __syncthreads();
  float e = expf(v0 - m) + expf(v1 - m);
  for (int o = 32; o > 0; o >>= 1) e += __shfl_down(e, o);
  if (lane == 0) wred[wid] = e;
  __syncthreads();
  float lse = m + logf(wred[0] + wred[1] + wred[2] + wred[3]);
  z[b * LL + t] = v0 - lse + gumbel[b * LL + t];
  z[b * LL + 256 + t] = v1 - lse + gumbel[b * LL + 256 + t];
}

// ---------------------------------------------------------------------------
// K3: selection. codes[b,l]: kept -> compact row (0..kp-1); pad -> kp; else -1
// row2l[b,r] = node position of compact row r. One block/batch, 512 threads.
// ---------------------------------------------------------------------------
__global__ __launch_bounds__(512) void k_select(
    const float* __restrict__ z, const int* __restrict__ k_per,
    const int* __restrict__ k_maxp, int* __restrict__ codes,
    int* __restrict__ row2l) {
  __shared__ float zs[LL];
  __shared__ int sel[LL];
  int b = blockIdx.x, l = threadIdx.x;
  int kp = k_per[b], km = *k_maxp;
  float zl = z[b * LL + l];
  zs[l] = zl;
  __syncthreads();
  int rank = 0;
  for (int j = 0; j < LL; ++j) {
    float zj = zs[j];
    rank += (zj > zl) || (zj == zl && j < l);
  }
  int s = (rank < km) ? 1 : 0;
  sel[l] = s;
  __syncthreads();
  int ps = 0;
  for (int j = 0; j < l; ++j) ps += sel[j];
  int kept = s && (ps < kp);
  int keptPrefix = min(ps, kp);
  int code;
  if (kept)
    code = ps;                       // compact row index
  else if ((l - keptPrefix) < (km - kp))
    code = kp;                       // pad-scatter position -> pad row kp
  else
    code = -1;                       // stays zero
  codes[b * LL + l] = code;
  if (kept) row2l[b * LL + ps] = l;
}

// ---------------------------------------------------------------------------
// K4: qkv in-proj for compact rows 0..kp (row kp = pad row with zero input,
// only when kp<512). 8 rows per block; thread t = channel t.
// ---------------------------------------------------------------------------
__global__ __launch_bounds__(256) void k_qkv(
    const float* __restrict__ x, const int* __restrict__ row2l,
    const int* __restrict__ k_per, const float* __restrict__ Win,
    const float* __restrict__ b_in, float* __restrict__ qb,
    float* __restrict__ kb, float* __restrict__ vb) {
  int b = blockIdx.y;
  int r0 = blockIdx.x * 8;
  int t = threadIdx.x;
  int kp = k_per[b];
  int rows = (kp < LL) ? kp + 1 : LL;
  if (r0 >= rows) return;
  __shared__ float xs[8][CC];
  int nv = min(8, rows - r0);
  for (int i = 0; i < nv; ++i) {
    int r = r0 + i;
    if (r < kp) {
      int l = row2l[b * LL + r];
      xs[i][t] = x[((size_t)b * LL + l) * CC + t];
    } else {
      xs[i][t] = 0.f;  // pad row: zero input -> qkv = b_in
    }
  }
  __syncthreads();
  float aq[8], ak[8], av[8];
#pragma unroll
  for (int i = 0; i < 8; ++i) { aq[i] = 0.f; ak[i] = 0.f; av[i] = 0.f; }
  const float* wq = Win + (size_t)t * CC;
  const float* wk = Win + (size_t)(CC + t) * CC;
  const float* wv = Win + (size_t)(2 * CC + t) * CC;
  for (int j = 0; j < CC; j += 4) {
    float4 q4 = *(const float4*)(wq + j);
    float4 k4 = *(const float4*)(wk + j);
    float4 v4 = *(const float4*)(wv + j);
#pragma unroll
    for (int i = 0; i < 8; ++i) {
      float x0 = xs[i][j], x1 = xs[i][j + 1], x2 = xs[i][j + 2], x3 = xs[i][j + 3];
      aq[i] += x0 * q4.x + x1 * q4.y + x2 * q4.z + x3 * q4.w;
      ak[i] += x0 * k4.x + x1 * k4.y + x2 * k4.z + x3 * k4.w;
      av[i] += x0 * v4.x + x1 * v4.y + x2 * v4.z + x3 * v4.w;
    }
  }
  float bq = b_in[t], bk2 = b_in[CC + t], bv2 = b_in[2 * CC + t];
  for (int i = 0; i < nv; ++i) {
    size_t o = ((size_t)b * LL + r0 + i) * CC + t;
    qb[o] = aq[i] + bq;
    kb[o] = ak[i] + bk2;
    vb[o] = av[i] + bv2;
  }
}

// ---------------------------------------------------------------------------
// K6 v2: flash-style attention. Block = (16-query chunk, head, batch),
// 256 threads. Stage q-tile once; loop 64-key tiles: K staged TRANSPOSED in
// LDS (Kt[d][key], pad 66 -> 2-way-free b64 reads); full score rows kept in
// LDS sc[16][516] -> exact 2-pass softmax; PV pass stages V[key][d] (pad 34).
// Output written in place over qb (block's own q rows only). ~43 KB LDS.
// ---------------------------------------------------------------------------
__global__ __launch_bounds__(256) void k_attn(float* __restrict__ qb,
                                              const float* __restrict__ kb,
                                              const float* __restrict__ vb,
                                              const int* __restrict__ k_per) {
  int h = blockIdx.y, b = blockIdx.z;
  int kp = k_per[b];
  int rows = (kp < LL) ? kp + 1 : LL;
  int q0 = blockIdx.x * 16;
  if (q0 >= rows) return;
  int t = threadIdx.x;

  __shared__ float qs[16][34];      // q tile (pad 34: rows 8B-aligned)
  __shared__ float sc[16][516];     // scores -> probabilities
  __shared__ float kvbuf[64 * 34];  // union: Kt[32][66] (scores) / V[64][34] (PV)

  size_t base = ((size_t)b * LL) * CC + (size_t)h * DHH;

  // stage q tile (zeros for rows beyond `rows` -> harmless scores)
  for (int idx = t; idx < 16 * 32; idx += 256) {
    int r = idx >> 5, d = idx & 31;
    int q = q0 + r;
    qs[r][d] = (q < rows) ? qb[base + (size_t)q * CC + d] : 0.f;
  }

  const float scale = 0.17677669529663687f;  // 1/sqrt(32)
  int nt = (kp + 63) >> 6;                   // live key tiles
  int qg = t >> 5, kk = t & 31;
  int r0 = qg * 2, r1 = r0 + 1;

  // ---- phase 1: scores ----
  for (int kt = 0; kt < nt; ++kt) {
    int k0 = kt << 6;
    __syncthreads();  // (iter 0 also covers qs staging)
    for (int idx = t; idx < 64 * 32; idx += 256) {
      int key = idx >> 5, d = idx & 31;
      int gk = k0 + key;
      kvbuf[d * 66 + key] = (gk < kp) ? kb[base + (size_t)gk * CC + d] : 0.f;
    }
    __syncthreads();
    float s00 = 0.f, s01 = 0.f, s10 = 0.f, s11 = 0.f;
#pragma unroll 8
    for (int d = 0; d < 32; ++d) {
      float q0v = qs[r0][d], q1v = qs[r1][d];
      float k0v = kvbuf[d * 66 + 2 * kk], k1v = kvbuf[d * 66 + 2 * kk + 1];
      s00 += q0v * k0v; s01 += q0v * k1v;
      s10 += q1v * k0v; s11 += q1v * k1v;
    }
    int c0 = k0 + 2 * kk;
    bool in0 = (c0 < kp), in1 = (c0 + 1 < kp);
    sc[r0][c0]     = in0 ? s00 * scale : -INFINITY;
    sc[r0][c0 + 1] = in1 ? s01 * scale : -INFINITY;
    sc[r1][c0]     = in0 ? s10 * scale : -INFINITY;
    sc[r1][c0 + 1] = in1 ? s11 * scale : -INFINITY;
  }
  __syncthreads();

  // ---- phase 2: exact softmax per row (16 threads/row) ----
  int r = t >> 4, i = t & 15;
  int ntk = nt << 6;
  float m = -INFINITY;
  for (int k = i; k < ntk; k += 16) m = fmaxf(m, sc[r][k]);
#pragma unroll
  for (int o = 1; o < 16; o <<= 1) m = fmaxf(m, __shfl_xor(m, o));
  float l = 0.f;
  for (int k = i; k < ntk; k += 16) l += expf(sc[r][k] - m);
#pragma unroll
  for (int o = 1; o < 16; o <<= 1) l += __shfl_xor(l, o);
  float inv = 1.f / l;
  for (int k = i; k < ntk; k += 16) sc[r][k] = expf(sc[r][k] - m) * inv;
  __syncthreads();

  // ---- phase 3: PV (thread = (row r, d pair dd)) ----
  int dd = (t & 15) * 2;
  float acc0 = 0.f, acc1 = 0.f;
  for (int kt = 0; kt < nt; ++kt) {
    int k0 = kt << 6;
    __syncthreads();
    for (int idx = t; idx < 64 * 32; idx += 256) {
      int key = idx >> 5, d = idx & 31;
      // rows >= kp hold finite garbage; p=0 kills them
      kvbuf[key * 34 + d] = vb[base + (size_t)(k0 + key) * CC + d];
    }
    __syncthreads();
#pragma unroll 8
    for (int k = 0; k < 64; ++k) {
      float p = sc[r][k0 + k];
      acc0 += p * kvbuf[k * 34 + dd];
      acc1 += p * kvbuf[k * 34 + dd + 1];
    }
  }
  int q = q0 + r;
  if (q < rows) {
    qb[base + (size_t)q * CC + dd] = acc0;
    qb[base + (size_t)q * CC + dd + 1] = acc1;
  }
}

// ---------------------------------------------------------------------------
// K7: out-proj + scatter + residual + ratio scale. 8 node positions / block.
// ---------------------------------------------------------------------------
__global__ __launch_bounds__(256) void k_outproj(
    const float* __restrict__ attnO, const int* __restrict__ codes,
    const float* __restrict__ Wout, const float* __restrict__ bout,
    const float* __restrict__ x, const float* __restrict__ ratio,
    float* __restrict__ out) {
  int b = blockIdx.y;
  int l0 = blockIdx.x * 8;
  int t = threadIdx.x;
  __shared__ float As[8][CC];
  __shared__ int cd[8];
  if (t < 8) cd[t] = codes[b * LL + l0 + t];
  __syncthreads();
  for (int i = 0; i < 8; ++i) {
    int c = cd[i];
    if (c >= 0) As[i][t] = attnO[((size_t)b * LL + c) * CC + t];
  }
  __syncthreads();
  float acc[8];
#pragma unroll
  for (int i = 0; i < 8; ++i) acc[i] = 0.f;
  const float* w = Wout + (size_t)t * CC;
  for (int j = 0; j < CC; j += 4) {
    float4 w4 = *(const float4*)(w + j);
#pragma unroll
    for (int i = 0; i < 8; ++i) {
      acc[i] += As[i][j] * w4.x + As[i][j + 1] * w4.y + As[i][j + 2] * w4.z +
                As[i][j + 3] * w4.w;
    }
  }
  float bo = bout[t], rt = ratio[b];
  for (int i = 0; i < 8; ++i) {
    int c = cd[i];
    float y = (c >= 0) ? (acc[i] + bo) : 0.f;
    size_t o = ((size_t)b * LL + l0 + i) * CC + t;
    out[o] = (y + x[o]) * rt;
  }
}

// ---------------------------------------------------------------------------
// K8: MLP residual: out += relu(out@Wm1^T + bm1)@Wm2^T + bm2. 8 tokens/block.
// ---------------------------------------------------------------------------
__global__ __launch_bounds__(256) void k_mlp(const float* __restrict__ Wm1,
                                             const float* __restrict__ bm1,
                                             const float* __restrict__ Wm2,
                                             const float* __restrict__ bm2,
                                             float* __restrict__ out) {
  __shared__ float hs[8][CC];
  __shared__ float ms[8][2 * CC];
  int tok0 = blockIdx.x * 8;
  int t = threadIdx.x;
  for (int i = 0; i < 8; ++i) hs[i][t] = out[(size_t)(tok0 + i) * CC + t];
  __syncthreads();
  float a0[8], a1[8];
#pragma unroll
  for (int i = 0; i < 8; ++i) { a0[i] = 0.f; a1[i] = 0.f; }
  const float* w0 = Wm1 + (size_t)t * CC;
  const float* w1 = Wm1 + (size_t)(CC + t) * CC;
  for (int j = 0; j < CC; j += 4) {
    float4 u0 = *(const float4*)(w0 + j);
    float4 u1 = *(const float4*)(w1 + j);
#pragma unroll
    for (int i = 0; i < 8; ++i) {
      float h0 = hs[i][j], h1 = hs[i][j + 1], h2 = hs[i][j + 2], h3 = hs[i][j + 3];
      a0[i] += h0 * u0.x + h1 * u0.y + h2 * u0.z + h3 * u0.w;
      a1[i] += h0 * u1.x + h1 * u1.y + h2 * u1.z + h3 * u1.w;
    }
  }
  float c0 = bm1[t], c1 = bm1[CC + t];
  for (int i = 0; i < 8; ++i) {
    ms[i][t] = fmaxf(a0[i] + c0, 0.f);
    ms[i][CC + t] = fmaxf(a1[i] + c1, 0.f);
  }
  __syncthreads();
  float a2[8];
#pragma unroll
  for (int i = 0; i < 8; ++i) a2[i] = 0.f;
  const float* w2 = Wm2 + (size_t)t * (2 * CC);
  for (int j = 0; j < 2 * CC; j += 4) {
    float4 w4 = *(const float4*)(w2 + j);
#pragma unroll
    for (int i = 0; i < 8; ++i) {
      a2[i] += ms[i][j] * w4.x + ms[i][j + 1] * w4.y + ms[i][j + 2] * w4.z +
               ms[i][j + 3] * w4.w;
    }
  }
  float c2 = bm2[t];
  for (int i = 0; i < 8; ++i)
    out[(size_t)(tok0 + i) * CC + t] = hs[i][t] + a2[i] + c2;
}

// ---------------------------------------------------------------------------
extern "C" void kernel_launch(void* const* d_in, const int* in_sizes, int n_in,
                              void* d_out, int out_size, void* d_ws,
                              size_t ws_size, hipStream_t stream) {
  (void)in_sizes; (void)n_in; (void)out_size; (void)ws_size;
  const float* x     = (const float*)d_in[0];
  const float* ratio = (const float*)d_in[3];
  const float* gum   = (const float*)d_in[4];
  const float* Ws1   = (const float*)d_in[5];
  const float* bs1   = (const float*)d_in[6];
  const float* Ws2   = (const float*)d_in[7];
  const float* bs2   = (const float*)d_in[8];
  const float* Win   = (const float*)d_in[9];
  const float* b_in  = (const float*)d_in[10];
  const float* Wout  = (const float*)d_in[11];
  const float* bout  = (const float*)d_in[12];
  const float* Wm1   = (const float*)d_in[13];
  const float* bm1   = (const float*)d_in[14];
  const float* Wm2   = (const float*)d_in[15];
  const float* bm2   = (const float*)d_in[16];
  float* out = (float*)d_out;

  float* z    = (float*)d_ws;            // N
  int* k_per  = (int*)(z + NN);          // 64 (+64 reserve)
  int* k_maxp = k_per + 64;
  int* codes  = k_per + 128;             // N
  int* row2l  = codes + NN;              // N
  float* qb   = (float*)(row2l + NN);    // B*L*C
  float* kb   = qb + (size_t)BB * LL * CC;
  float* vb   = kb + (size_t)BB * LL * CC;

  k_scorer<<<NN / 8, 256, 0, stream>>>(x, Ws1, bs1, Ws2, bs2, z);
  k_kper<<<1, 64, 0, stream>>>(ratio, k_per, k_maxp);
  k_lsg<<<BB, 256, 0, stream>>>(z, gum);
  k_select<<<BB, 512, 0, stream>>>(z, k_per, k_maxp, codes, row2l);
  k_qkv<<<dim3(64, BB), 256, 0, stream>>>(x, row2l, k_per, Win, b_in, qb, kb, vb);
  k_attn<<<dim3(LL / 16, HH, BB), 256, 0, stream>>>(qb, kb, vb, k_per);
  k_outproj<<<dim3(64, BB), 256, 0, stream>>>(qb, codes, Wout, bout, x, ratio, out);
  k_mlp<<<NN / 8, 256, 0, stream>>>(Wm1, bm1, Wm2, bm2, out);
}

// Round 3
// 1147.639 us; speedup vs baseline: 3.4560x; 1.9861x over previous
//
#include <hip/hip_runtime.h>
#include <hip/hip_bf16.h>
#include <math.h>

// Problem constants (from reference)
#define BB 64
#define LL 512
#define CC 256
#define HH 8
#define DHH 32
#define NN (BB * LL)

typedef __attribute__((ext_vector_type(8))) short bf16x8;   // MFMA A/B frag
typedef __attribute__((ext_vector_type(4))) float f32x4;    // MFMA C/D frag
typedef __attribute__((ext_vector_type(4))) unsigned short us4;

#define MFMA16(a, b, c) __builtin_amdgcn_mfma_f32_16x16x32_bf16(a, b, c, 0, 0, 0)

__device__ __forceinline__ unsigned short f2bf(float f) {
  unsigned u = __builtin_bit_cast(unsigned, f);
  u += 0x7fffu + ((u >> 16) & 1u);  // RNE
  return (unsigned short)(u >> 16);
}
__device__ __forceinline__ float bf2f(unsigned short h) {
  unsigned u = ((unsigned)h) << 16;
  return __builtin_bit_cast(float, u);
}

// ---------------------------------------------------------------------------
// K0: fp32 -> bf16 bulk convert
// ---------------------------------------------------------------------------
__global__ __launch_bounds__(256) void k_f2bf(const float* __restrict__ src,
                                              unsigned short* __restrict__ dst,
                                              int n) {
  int i = blockIdx.x * 256 + threadIdx.x;
  if (i < n) dst[i] = f2bf(src[i]);
}

// ---------------------------------------------------------------------------
// K1: scorer (EXACT fp32 — selection depends on it; do not quantize).
// ---------------------------------------------------------------------------
__global__ __launch_bounds__(256) void k_scorer(
    const float* __restrict__ x, const float* __restrict__ Ws1,
    const float* __restrict__ bs1, const float* __restrict__ Ws2,
    const float* __restrict__ bs2, float* __restrict__ scores) {
  __shared__ float xs[8][CC];
  __shared__ float wred[8][4];
  int t = threadIdx.x;
  int lane = t & 63, wid = t >> 6;
  int tok0 = blockIdx.x * 8;
  for (int i = 0; i < 8; ++i) xs[i][t] = x[(size_t)(tok0 + i) * CC + t];
  __syncthreads();
  float acc[8];
#pragma unroll
  for (int i = 0; i < 8; ++i) acc[i] = 0.f;
  const float* wrow = Ws1 + (size_t)t * CC;
  for (int j = 0; j < CC; j += 4) {
    float4 w = *(const float4*)(wrow + j);
#pragma unroll
    for (int i = 0; i < 8; ++i) {
      acc[i] += xs[i][j] * w.x + xs[i][j + 1] * w.y + xs[i][j + 2] * w.z +
                xs[i][j + 3] * w.w;
    }
  }
  float b1 = bs1[t], w2 = Ws2[t];
#pragma unroll
  for (int i = 0; i < 8; ++i) {
    float v = fmaxf(acc[i] + b1, 0.f) * w2;
    for (int o = 32; o > 0; o >>= 1) v += __shfl_down(v, o);
    if (lane == 0) wred[i][wid] = v;
  }
  __syncthreads();
  if (t < 8)
    scores[tok0 + t] = wred[t][0] + wred[t][1] + wred[t][2] + wred[t][3] + bs2[0];
}

// ---------------------------------------------------------------------------
// K2a: k_per / k_max
// ---------------------------------------------------------------------------
__global__ __launch_bounds__(64) void k_kper(const float* __restrict__ ratio,
                                             int* __restrict__ k_per,
                                             int* __restrict__ k_maxp) {
  int t = threadIdx.x;
  int kp = (int)ceilf(ratio[t] * (float)LL);
  kp = min(max(kp, 1), LL);
  k_per[t] = kp;
  int m = kp;
  for (int o = 32; o > 0; o >>= 1) m = max(m, __shfl_down(m, o));
  if (t == 0) *k_maxp = m;
}

// ---------------------------------------------------------------------------
// K2: z = log_softmax(scores) + gumbel (in place, fp32)
// ---------------------------------------------------------------------------
__global__ __launch_bounds__(256) void k_lsg(float* __restrict__ z,
                                             const float* __restrict__ gumbel) {
  int b = blockIdx.x, t = threadIdx.x;
  int lane = t & 63, wid = t >> 6;
  __shared__ float wred[4];
  float v0 = z[b * LL + t], v1 = z[b * LL + 256 + t];
  float m = fmaxf(v0, v1);
  for (int o = 32; o > 0; o >>= 1) m = fmaxf(m, __shfl_down(m, o));
  if (lane == 0) wred[wid] = m;
  __syncthreads();
  m = fmaxf(fmaxf(wred[0], wred[1]), fmaxf(wred[2], wred[3]));
  __syncthreads();
  float e = expf(v0 - m) + expf(v1 - m);
  for (int o = 32; o > 0; o >>= 1) e += __shfl_down(e, o);
  if (lane == 0) wred[wid] = e;
  __syncthreads();
  float lse = m + logf(wred[0] + wred[1] + wred[2] + wred[3]);
  z[b * LL + t] = v0 - lse + gumbel[b * LL + t];
  z[b * LL + 256 + t] = v1 - lse + gumbel[b * LL + 256 + t];
}

// ---------------------------------------------------------------------------
// K3: selection (fp32, unchanged)
// ---------------------------------------------------------------------------
__global__ __launch_bounds__(512) void k_select(
    const float* __restrict__ z, const int* __restrict__ k_per,
    const int* __restrict__ k_maxp, int* __restrict__ codes,
    int* __restrict__ row2l) {
  __shared__ float zs[LL];
  __shared__ int sel[LL];
  int b = blockIdx.x, l = threadIdx.x;
  int kp = k_per[b], km = *k_maxp;
  float zl = z[b * LL + l];
  zs[l] = zl;
  __syncthreads();
  int rank = 0;
  for (int j = 0; j < LL; ++j) {
    float zj = zs[j];
    rank += (zj > zl) || (zj == zl && j < l);
  }
  int s = (rank < km) ? 1 : 0;
  sel[l] = s;
  __syncthreads();
  int ps = 0;
  for (int j = 0; j < l; ++j) ps += sel[j];
  int kept = s && (ps < kp);
  int keptPrefix = min(ps, kp);
  int code;
  if (kept)
    code = ps;
  else if ((l - keptPrefix) < (km - kp))
    code = kp;
  else
    code = -1;
  codes[b * LL + l] = code;
  if (kept) row2l[b * LL + ps] = l;
}

// ---------------------------------------------------------------------------
// K4 v2: qkv in-proj via bf16 MFMA. Block = 32 compact rows, 256 thr = 4
// waves; wave w owns 192 of the 768 output cols (12 col-tiles). A gathered
// from x_bf16 into LDS [32][264] (pad -> 2-way-free b128 frag reads); B-frags
// (Win^T) read directly from L2-resident bf16 weights. Outputs bf16.
// ---------------------------------------------------------------------------
__global__ __launch_bounds__(256) void k_qkv(
    const unsigned short* __restrict__ xh, const int* __restrict__ row2l,
    const int* __restrict__ k_per, const unsigned short* __restrict__ Winh,
    const float* __restrict__ b_in, unsigned short* __restrict__ qh,
    unsigned short* __restrict__ kh, unsigned short* __restrict__ vh) {
  int b = blockIdx.y;
  int kp = k_per[b];
  int rows = (kp < LL) ? kp + 1 : LL;
  int r0 = blockIdx.x * 32;
  if (r0 >= rows) return;
  __shared__ unsigned short A1[32][264];
  int t = threadIdx.x;
  for (int idx = t; idx < 32 * 64; idx += 256) {
    int r = idx >> 6, c4 = idx & 63;
    int gr = r0 + r;
    us4 v = {0, 0, 0, 0};
    if (gr < kp) {
      int l = row2l[b * LL + gr];
      v = ((const us4*)(xh + ((size_t)b * LL + l) * CC))[c4];
    }
    *(us4*)&A1[r][c4 * 4] = v;
  }
  __syncthreads();
  int lane = t & 63, wid = t >> 6, quad = lane >> 4, row16 = lane & 15;
  f32x4 acc[2][12] = {};
  for (int k0 = 0; k0 < CC; k0 += 32) {
    bf16x8 a0 = *(const bf16x8*)&A1[row16][k0 + quad * 8];
    bf16x8 a1 = *(const bf16x8*)&A1[16 + row16][k0 + quad * 8];
#pragma unroll
    for (int nt = 0; nt < 12; ++nt) {
      int n = wid * 192 + nt * 16 + row16;
      bf16x8 bfr = *(const bf16x8*)&Winh[(size_t)n * CC + k0 + quad * 8];
      acc[0][nt] = MFMA16(a0, bfr, acc[0][nt]);
      acc[1][nt] = MFMA16(a1, bfr, acc[1][nt]);
    }
  }
#pragma unroll
  for (int rt = 0; rt < 2; ++rt) {
#pragma unroll
    for (int nt = 0; nt < 12; ++nt) {
      int n = wid * 192 + nt * 16 + row16;  // 0..767
      int which = n >> 8, nc = n & 255;
      unsigned short* dst = (which == 0) ? qh : (which == 1) ? kh : vh;
      float bias = b_in[n];
#pragma unroll
      for (int r = 0; r < 4; ++r) {
        int row = r0 + rt * 16 + quad * 4 + r;
        if (row < rows)
          dst[((size_t)b * LL + row) * CC + nc] = f2bf(acc[rt][nt][r] + bias);
      }
    }
  }
}

// ---------------------------------------------------------------------------
// K6: flash-style attention (fp32 math, bf16 I/O). Writes bf16 to ah.
// ---------------------------------------------------------------------------
__global__ __launch_bounds__(256) void k_attn(
    const unsigned short* __restrict__ qh, const unsigned short* __restrict__ kh,
    const unsigned short* __restrict__ vh, const int* __restrict__ k_per,
    unsigned short* __restrict__ ah) {
  int h = blockIdx.y, b = blockIdx.z;
  int kp = k_per[b];
  int rows = (kp < LL) ? kp + 1 : LL;
  int q0 = blockIdx.x * 16;
  if (q0 >= rows) return;
  int t = threadIdx.x;

  __shared__ float qs[16][34];
  __shared__ float sc[16][516];
  __shared__ float kvbuf[64 * 34];

  size_t base = ((size_t)b * LL) * CC + (size_t)h * DHH;

  for (int idx = t; idx < 16 * 32; idx += 256) {
    int r = idx >> 5, d = idx & 31;
    int q = q0 + r;
    qs[r][d] = (q < rows) ? bf2f(qh[base + (size_t)q * CC + d]) : 0.f;
  }

  const float scale = 0.17677669529663687f;  // 1/sqrt(32)
  int nt = (kp + 63) >> 6;
  int qg = t >> 5, kk = t & 31;
  int r0 = qg * 2, r1 = r0 + 1;

  for (int kt = 0; kt < nt; ++kt) {
    int k0 = kt << 6;
    __syncthreads();
    for (int idx = t; idx < 64 * 32; idx += 256) {
      int key = idx >> 5, d = idx & 31;
      int gk = k0 + key;
      kvbuf[d * 66 + key] = (gk < kp) ? bf2f(kh[base + (size_t)gk * CC + d]) : 0.f;
    }
    __syncthreads();
    float s00 = 0.f, s01 = 0.f, s10 = 0.f, s11 = 0.f;
#pragma unroll 8
    for (int d = 0; d < 32; ++d) {
      float q0v = qs[r0][d], q1v = qs[r1][d];
      float k0v = kvbuf[d * 66 + 2 * kk], k1v = kvbuf[d * 66 + 2 * kk + 1];
      s00 += q0v * k0v; s01 += q0v * k1v;
      s10 += q1v * k0v; s11 += q1v * k1v;
    }
    int c0 = k0 + 2 * kk;
    bool in0 = (c0 < kp), in1 = (c0 + 1 < kp);
    sc[r0][c0]     = in0 ? s00 * scale : -INFINITY;
    sc[r0][c0 + 1] = in1 ? s01 * scale : -INFINITY;
    sc[r1][c0]     = in0 ? s10 * scale : -INFINITY;
    sc[r1][c0 + 1] = in1 ? s11 * scale : -INFINITY;
  }
  __syncthreads();

  int r = t >> 4, i = t & 15;
  int ntk = nt << 6;
  float m = -INFINITY;
  for (int k = i; k < ntk; k += 16) m = fmaxf(m, sc[r][k]);
#pragma unroll
  for (int o = 1; o < 16; o <<= 1) m = fmaxf(m, __shfl_xor(m, o));
  float l = 0.f;
  for (int k = i; k < ntk; k += 16) l += expf(sc[r][k] - m);
#pragma unroll
  for (int o = 1; o < 16; o <<= 1) l += __shfl_xor(l, o);
  float inv = 1.f / l;
  for (int k = i; k < ntk; k += 16) sc[r][k] = expf(sc[r][k] - m) * inv;
  __syncthreads();

  int dd = (t & 15) * 2;
  float acc0 = 0.f, acc1 = 0.f;
  for (int kt = 0; kt < nt; ++kt) {
    int k0 = kt << 6;
    __syncthreads();
    for (int idx = t; idx < 64 * 32; idx += 256) {
      int key = idx >> 5, d = idx & 31;
      kvbuf[key * 34 + d] = bf2f(vh[base + (size_t)(k0 + key) * CC + d]);
    }
    __syncthreads();
#pragma unroll 8
    for (int k = 0; k < 64; ++k) {
      float p = sc[r][k0 + k];
      acc0 += p * kvbuf[k * 34 + dd];
      acc1 += p * kvbuf[k * 34 + dd + 1];
    }
  }
  int q = q0 + r;
  if (q < rows) {
    ah[base + (size_t)q * CC + dd] = f2bf(acc0);
    ah[base + (size_t)q * CC + dd + 1] = f2bf(acc1);
  }
}

// ---------------------------------------------------------------------------
// K7 v2: out-proj via bf16 MFMA + scatter + residual + ratio. Block = 32 node
// positions; wave owns 64 cols (4 col-tiles). Writes out fp32 + outh bf16.
// ---------------------------------------------------------------------------
__global__ __launch_bounds__(256) void k_outproj(
    const unsigned short* __restrict__ ah, const int* __restrict__ codes,
    const unsigned short* __restrict__ Wouth, const float* __restrict__ bout,
    const float* __restrict__ x, const float* __restrict__ ratio,
    float* __restrict__ out, unsigned short* __restrict__ outh) {
  int b = blockIdx.y;
  int l0 = blockIdx.x * 32;
  int t = threadIdx.x;
  __shared__ unsigned short A1[32][264];
  __shared__ int cd[32];
  if (t < 32) cd[t] = codes[b * LL + l0 + t];
  __syncthreads();
  for (int idx = t; idx < 32 * 64; idx += 256) {
    int r = idx >> 6, c4 = idx & 63;
    int c = cd[r];
    us4 v = {0, 0, 0, 0};
    if (c >= 0) v = ((const us4*)(ah + ((size_t)b * LL + c) * CC))[c4];
    *(us4*)&A1[r][c4 * 4] = v;
  }
  __syncthreads();
  int lane = t & 63, wid = t >> 6, quad = lane >> 4, row16 = lane & 15;
  f32x4 acc[2][4] = {};
  for (int k0 = 0; k0 < CC; k0 += 32) {
    bf16x8 a0 = *(const bf16x8*)&A1[row16][k0 + quad * 8];
    bf16x8 a1 = *(const bf16x8*)&A1[16 + row16][k0 + quad * 8];
#pragma unroll
    for (int nt = 0; nt < 4; ++nt) {
      int n = wid * 64 + nt * 16 + row16;
      bf16x8 bfr = *(const bf16x8*)&Wouth[(size_t)n * CC + k0 + quad * 8];
      acc[0][nt] = MFMA16(a0, bfr, acc[0][nt]);
      acc[1][nt] = MFMA16(a1, bfr, acc[1][nt]);
    }
  }
  float rt_ratio = ratio[b];
#pragma unroll
  for (int rt = 0; rt < 2; ++rt) {
#pragma unroll
    for (int nt = 0; nt < 4; ++nt) {
      int n = wid * 64 + nt * 16 + row16;
      float bias = bout[n];
#pragma unroll
      for (int r = 0; r < 4; ++r) {
        int rl = rt * 16 + quad * 4 + r;
        int c = cd[rl];
        float y = (c >= 0) ? (acc[rt][nt][r] + bias) : 0.f;
        size_t o = ((size_t)b * LL + l0 + rl) * CC + n;
        float res = (y + x[o]) * rt_ratio;
        out[o] = res;
        outh[o] = f2bf(res);
      }
    }
  }
}

// ---------------------------------------------------------------------------
// K8 v2: fused MLP via bf16 MFMA. Block = 32 tokens, 4 waves. GEMM1 (K=256,
// N=512): wave owns 128 cols -> relu -> bf16 LDS Hs[32][520]; GEMM2 (K=512,
// N=256): wave owns 64 cols -> + bias + fp32 residual from out -> out.
// ---------------------------------------------------------------------------
__global__ __launch_bounds__(256) void k_mlp(
    const unsigned short* __restrict__ outh,
    const unsigned short* __restrict__ Wm1h, const float* __restrict__ bm1,
    const unsigned short* __restrict__ Wm2h, const float* __restrict__ bm2,
    float* __restrict__ out) {
  __shared__ unsigned short A1[32][264];
  __shared__ unsigned short Hs[32][520];
  int t = threadIdx.x;
  int tok0 = blockIdx.x * 32;
  for (int idx = t; idx < 32 * 64; idx += 256) {
    int r = idx >> 6, c4 = idx & 63;
    *(us4*)&A1[r][c4 * 4] =
        ((const us4*)(outh + (size_t)(tok0 + r) * CC))[c4];
  }
  __syncthreads();
  int lane = t & 63, wid = t >> 6, quad = lane >> 4, row16 = lane & 15;

  // GEMM1: hidden = relu(A @ Wm1^T + bm1), cols [wid*128, wid*128+128)
  f32x4 acc1[2][8] = {};
  for (int k0 = 0; k0 < CC; k0 += 32) {
    bf16x8 a0 = *(const bf16x8*)&A1[row16][k0 + quad * 8];
    bf16x8 a1 = *(const bf16x8*)&A1[16 + row16][k0 + quad * 8];
#pragma unroll
    for (int nt = 0; nt < 8; ++nt) {
      int n = wid * 128 + nt * 16 + row16;
      bf16x8 bfr = *(const bf16x8*)&Wm1h[(size_t)n * CC + k0 + quad * 8];
      acc1[0][nt] = MFMA16(a0, bfr, acc1[0][nt]);
      acc1[1][nt] = MFMA16(a1, bfr, acc1[1][nt]);
    }
  }
#pragma unroll
  for (int rt = 0; rt < 2; ++rt) {
#pragma unroll
    for (int nt = 0; nt < 8; ++nt) {
      int n = wid * 128 + nt * 16 + row16;
      float bias = bm1[n];
#pragma unroll
      for (int r = 0; r < 4; ++r) {
        float v = fmaxf(acc1[rt][nt][r] + bias, 0.f);
        Hs[rt * 16 + quad * 4 + r][n] = f2bf(v);
      }
    }
  }
  __syncthreads();

  // GEMM2: out += Hs @ Wm2^T + bm2, cols [wid*64, wid*64+64)
  f32x4 acc2[2][4] = {};
  for (int k0 = 0; k0 < 2 * CC; k0 += 32) {
    bf16x8 a0 = *(const bf16x8*)&Hs[row16][k0 + quad * 8];
    bf16x8 a1 = *(const bf16x8*)&Hs[16 + row16][k0 + quad * 8];
#pragma unroll
    for (int nt = 0; nt < 4; ++nt) {
      int n = wid * 64 + nt * 16 + row16;
      bf16x8 bfr = *(const bf16x8*)&Wm2h[(size_t)n * (2 * CC) + k0 + quad * 8];
      acc2[0][nt] = MFMA16(a0, bfr, acc2[0][nt]);
      acc2[1][nt] = MFMA16(a1, bfr, acc2[1][nt]);
    }
  }
#pragma unroll
  for (int rt = 0; rt < 2; ++rt) {
#pragma unroll
    for (int nt = 0; nt < 4; ++nt) {
      int n = wid * 64 + nt * 16 + row16;
      float bias = bm2[n];
#pragma unroll
      for (int r = 0; r < 4; ++r) {
        size_t o = (size_t)(tok0 + rt * 16 + quad * 4 + r) * CC + n;
        out[o] = out[o] + acc2[rt][nt][r] + bias;
      }
    }
  }
}

// ---------------------------------------------------------------------------
extern "C" void kernel_launch(void* const* d_in, const int* in_sizes, int n_in,
                              void* d_out, int out_size, void* d_ws,
                              size_t ws_size, hipStream_t stream) {
  (void)in_sizes; (void)n_in; (void)out_size; (void)ws_size;
  const float* x     = (const float*)d_in[0];
  const float* ratio = (const float*)d_in[3];
  const float* gum   = (const float*)d_in[4];
  const float* Ws1   = (const float*)d_in[5];
  const float* bs1   = (const float*)d_in[6];
  const float* Ws2   = (const float*)d_in[7];
  const float* bs2   = (const float*)d_in[8];
  const float* Win   = (const float*)d_in[9];
  const float* b_in  = (const float*)d_in[10];
  const float* Wout  = (const float*)d_in[11];
  const float* bout  = (const float*)d_in[12];
  const float* Wm1   = (const float*)d_in[13];
  const float* bm1   = (const float*)d_in[14];
  const float* Wm2   = (const float*)d_in[15];
  const float* bm2   = (const float*)d_in[16];
  float* out = (float*)d_out;

  // workspace layout
  const size_t NXC = (size_t)NN * CC;  // 8388608
  float* z    = (float*)d_ws;                     // N f32
  int* k_per  = (int*)(z + NN);                   // 128 ints
  int* k_maxp = k_per + 64;
  int* codes  = k_per + 128;                      // N ints
  int* row2l  = codes + NN;                       // N ints
  unsigned short* xh    = (unsigned short*)(row2l + NN);  // N*C bf16
  unsigned short* qh    = xh + NXC;
  unsigned short* kh    = qh + NXC;
  unsigned short* vh    = kh + NXC;
  unsigned short* ahb   = vh + NXC;
  unsigned short* outh  = ahb + NXC;
  unsigned short* Winh  = outh + NXC;             // 196608
  unsigned short* Wouth = Winh + 3 * CC * CC;     // 65536
  unsigned short* Wm1h  = Wouth + CC * CC;        // 131072
  unsigned short* Wm2h  = Wm1h + 2 * CC * CC;     // 131072

  k_f2bf<<<(int)((NXC + 255) / 256), 256, 0, stream>>>(x, xh, (int)NXC);
  k_f2bf<<<(3 * CC * CC + 255) / 256, 256, 0, stream>>>(Win, Winh, 3 * CC * CC);
  k_f2bf<<<(CC * CC + 255) / 256, 256, 0, stream>>>(Wout, Wouth, CC * CC);
  k_f2bf<<<(2 * CC * CC + 255) / 256, 256, 0, stream>>>(Wm1, Wm1h, 2 * CC * CC);
  k_f2bf<<<(2 * CC * CC + 255) / 256, 256, 0, stream>>>(Wm2, Wm2h, 2 * CC * CC);

  k_scorer<<<NN / 8, 256, 0, stream>>>(x, Ws1, bs1, Ws2, bs2, z);
  k_kper<<<1, 64, 0, stream>>>(ratio, k_per, k_maxp);
  k_lsg<<<BB, 256, 0, stream>>>(z, gum);
  k_select<<<BB, 512, 0, stream>>>(z, k_per, k_maxp, codes, row2l);
  k_qkv<<<dim3(16, BB), 256, 0, stream>>>(xh, row2l, k_per, Winh, b_in, qh, kh, vh);
  k_attn<<<dim3(LL / 16, HH, BB), 256, 0, stream>>>(qh, kh, vh, k_per, ahb);
  k_outproj<<<dim3(16, BB), 256, 0, stream>>>(ahb, codes, Wouth, bout, x, ratio, out, outh);
  k_mlp<<<NN / 32, 256, 0, stream>>>(outh, Wm1h, bm1, Wm2h, bm2, out);
}

// Round 4
// 705.390 us; speedup vs baseline: 5.6227x; 1.6270x over previous
//
#include <hip/hip_runtime.h>
#include <hip/hip_bf16.h>
#include <math.h>

// Problem constants (from reference)
#define BB 64
#define LL 512
#define CC 256
#define HH 8
#define DHH 32
#define NN (BB * LL)

typedef __attribute__((ext_vector_type(8))) short bf16x8;   // MFMA A/B frag
typedef __attribute__((ext_vector_type(4))) float f32x4;    // MFMA C/D frag
typedef __attribute__((ext_vector_type(4))) unsigned short us4;

#define MFMA16(a, b, c) __builtin_amdgcn_mfma_f32_16x16x32_bf16(a, b, c, 0, 0, 0)

__device__ __forceinline__ unsigned short f2bf(float f) {
  unsigned u = __builtin_bit_cast(unsigned, f);
  u += 0x7fffu + ((u >> 16) & 1u);  // RNE
  return (unsigned short)(u >> 16);
}
__device__ __forceinline__ float bf2f(unsigned short h) {
  unsigned u = ((unsigned)h) << 16;
  return __builtin_bit_cast(float, u);
}

// ---------------------------------------------------------------------------
// K0: fp32 -> bf16 bulk convert
// ---------------------------------------------------------------------------
__global__ __launch_bounds__(256) void k_f2bf(const float* __restrict__ src,
                                              unsigned short* __restrict__ dst,
                                              int n) {
  int i = blockIdx.x * 256 + threadIdx.x;
  if (i < n) dst[i] = f2bf(src[i]);
}

// ---------------------------------------------------------------------------
// K1: scorer (EXACT fp32 — selection depends on it; do not quantize).
// ---------------------------------------------------------------------------
__global__ __launch_bounds__(256) void k_scorer(
    const float* __restrict__ x, const float* __restrict__ Ws1,
    const float* __restrict__ bs1, const float* __restrict__ Ws2,
    const float* __restrict__ bs2, float* __restrict__ scores) {
  __shared__ float xs[8][CC];
  __shared__ float wred[8][4];
  int t = threadIdx.x;
  int lane = t & 63, wid = t >> 6;
  int tok0 = blockIdx.x * 8;
  for (int i = 0; i < 8; ++i) xs[i][t] = x[(size_t)(tok0 + i) * CC + t];
  __syncthreads();
  float acc[8];
#pragma unroll
  for (int i = 0; i < 8; ++i) acc[i] = 0.f;
  const float* wrow = Ws1 + (size_t)t * CC;
  for (int j = 0; j < CC; j += 4) {
    float4 w = *(const float4*)(wrow + j);
#pragma unroll
    for (int i = 0; i < 8; ++i) {
      acc[i] += xs[i][j] * w.x + xs[i][j + 1] * w.y + xs[i][j + 2] * w.z +
                xs[i][j + 3] * w.w;
    }
  }
  float b1 = bs1[t], w2 = Ws2[t];
#pragma unroll
  for (int i = 0; i < 8; ++i) {
    float v = fmaxf(acc[i] + b1, 0.f) * w2;
    for (int o = 32; o > 0; o >>= 1) v += __shfl_down(v, o);
    if (lane == 0) wred[i][wid] = v;
  }
  __syncthreads();
  if (t < 8)
    scores[tok0 + t] = wred[t][0] + wred[t][1] + wred[t][2] + wred[t][3] + bs2[0];
}

// ---------------------------------------------------------------------------
// K2a: k_per / k_max
// ---------------------------------------------------------------------------
__global__ __launch_bounds__(64) void k_kper(const float* __restrict__ ratio,
                                             int* __restrict__ k_per,
                                             int* __restrict__ k_maxp) {
  int t = threadIdx.x;
  int kp = (int)ceilf(ratio[t] * (float)LL);
  kp = min(max(kp, 1), LL);
  k_per[t] = kp;
  int m = kp;
  for (int o = 32; o > 0; o >>= 1) m = max(m, __shfl_down(m, o));
  if (t == 0) *k_maxp = m;
}

// ---------------------------------------------------------------------------
// K2: z = log_softmax(scores) + gumbel (in place, fp32)
// ---------------------------------------------------------------------------
__global__ __launch_bounds__(256) void k_lsg(float* __restrict__ z,
                                             const float* __restrict__ gumbel) {
  int b = blockIdx.x, t = threadIdx.x;
  int lane = t & 63, wid = t >> 6;
  __shared__ float wred[4];
  float v0 = z[b * LL + t], v1 = z[b * LL + 256 + t];
  float m = fmaxf(v0, v1);
  for (int o = 32; o > 0; o >>= 1) m = fmaxf(m, __shfl_down(m, o));
  if (lane == 0) wred[wid] = m;
  __syncthreads();
  m = fmaxf(fmaxf(wred[0], wred[1]), fmaxf(wred[2], wred[3]));
  __syncthreads();
  float e = expf(v0 - m) + expf(v1 - m);
  for (int o = 32; o > 0; o >>= 1) e += __shfl_down(e, o);
  if (lane == 0) wred[wid] = e;
  __syncthreads();
  float lse = m + logf(wred[0] + wred[1] + wred[2] + wred[3]);
  z[b * LL + t] = v0 - lse + gumbel[b * LL + t];
  z[b * LL + 256 + t] = v1 - lse + gumbel[b * LL + 256 + t];
}

// ---------------------------------------------------------------------------
// K3: selection (fp32, unchanged)
// ---------------------------------------------------------------------------
__global__ __launch_bounds__(512) void k_select(
    const float* __restrict__ z, const int* __restrict__ k_per,
    const int* __restrict__ k_maxp, int* __restrict__ codes,
    int* __restrict__ row2l) {
  __shared__ float zs[LL];
  __shared__ int sel[LL];
  int b = blockIdx.x, l = threadIdx.x;
  int kp = k_per[b], km = *k_maxp;
  float zl = z[b * LL + l];
  zs[l] = zl;
  __syncthreads();
  int rank = 0;
  for (int j = 0; j < LL; ++j) {
    float zj = zs[j];
    rank += (zj > zl) || (zj == zl && j < l);
  }
  int s = (rank < km) ? 1 : 0;
  sel[l] = s;
  __syncthreads();
  int ps = 0;
  for (int j = 0; j < l; ++j) ps += sel[j];
  int kept = s && (ps < kp);
  int keptPrefix = min(ps, kp);
  int code;
  if (kept)
    code = ps;
  else if ((l - keptPrefix) < (km - kp))
    code = kp;
  else
    code = -1;
  codes[b * LL + l] = code;
  if (kept) row2l[b * LL + ps] = l;
}

// ---------------------------------------------------------------------------
// K4: qkv in-proj via bf16 MFMA (unchanged from R2).
// ---------------------------------------------------------------------------
__global__ __launch_bounds__(256) void k_qkv(
    const unsigned short* __restrict__ xh, const int* __restrict__ row2l,
    const int* __restrict__ k_per, const unsigned short* __restrict__ Winh,
    const float* __restrict__ b_in, unsigned short* __restrict__ qh,
    unsigned short* __restrict__ kh, unsigned short* __restrict__ vh) {
  int b = blockIdx.y;
  int kp = k_per[b];
  int rows = (kp < LL) ? kp + 1 : LL;
  int r0 = blockIdx.x * 32;
  if (r0 >= rows) return;
  __shared__ unsigned short A1[32][264];
  int t = threadIdx.x;
  for (int idx = t; idx < 32 * 64; idx += 256) {
    int r = idx >> 6, c4 = idx & 63;
    int gr = r0 + r;
    us4 v = {0, 0, 0, 0};
    if (gr < kp) {
      int l = row2l[b * LL + gr];
      v = ((const us4*)(xh + ((size_t)b * LL + l) * CC))[c4];
    }
    *(us4*)&A1[r][c4 * 4] = v;
  }
  __syncthreads();
  int lane = t & 63, wid = t >> 6, quad = lane >> 4, row16 = lane & 15;
  f32x4 acc[2][12] = {};
  for (int k0 = 0; k0 < CC; k0 += 32) {
    bf16x8 a0 = *(const bf16x8*)&A1[row16][k0 + quad * 8];
    bf16x8 a1 = *(const bf16x8*)&A1[16 + row16][k0 + quad * 8];
#pragma unroll
    for (int nt = 0; nt < 12; ++nt) {
      int n = wid * 192 + nt * 16 + row16;
      bf16x8 bfr = *(const bf16x8*)&Winh[(size_t)n * CC + k0 + quad * 8];
      acc[0][nt] = MFMA16(a0, bfr, acc[0][nt]);
      acc[1][nt] = MFMA16(a1, bfr, acc[1][nt]);
    }
  }
#pragma unroll
  for (int rt = 0; rt < 2; ++rt) {
#pragma unroll
    for (int nt = 0; nt < 12; ++nt) {
      int n = wid * 192 + nt * 16 + row16;  // 0..767
      int which = n >> 8, nc = n & 255;
      unsigned short* dst = (which == 0) ? qh : (which == 1) ? kh : vh;
      float bias = b_in[n];
#pragma unroll
      for (int r = 0; r < 4; ++r) {
        int row = r0 + rt * 16 + quad * 4 + r;
        if (row < rows)
          dst[((size_t)b * LL + row) * CC + nc] = f2bf(acc[rt][nt][r] + bias);
      }
    }
  }
}

// ---------------------------------------------------------------------------
// K6 v3: MFMA attention. Block = (64-query chunk, head, batch), 256 thr = 4
// waves, each wave 16 queries. Scores: A=Q frag (direct global), B=K rows
// staged in LDS K[128][40] per 128-key chunk; one MFMA per 16x16 tile (K=32
// = full head dim). All 512 scores in registers (32 x f32x4). Exact softmax
// in registers (per-lane bias mask, 16-lane butterflies, single __expf).
// PV: P -> wave-private LDS [16][40] (A-layout round-trip, lgkmcnt wait),
// B = V^T staged per chunk into the same LDS union (pitch 132, b64 reads).
// LDS ~15.4 KB. Output bf16 to ah.
// ---------------------------------------------------------------------------
__global__ __launch_bounds__(256) void k_attn(
    const unsigned short* __restrict__ qh, const unsigned short* __restrict__ kh,
    const unsigned short* __restrict__ vh, const int* __restrict__ k_per,
    unsigned short* __restrict__ ah) {
  int h = blockIdx.y, b = blockIdx.z;
  int kp = k_per[b];
  int rows = (kp < LL) ? kp + 1 : LL;
  int q0 = blockIdx.x * 64;
  if (q0 >= rows) return;
  int t = threadIdx.x;
  int lane = t & 63, wid = t >> 6;
  int quad = lane >> 4, l16 = lane & 15;  // l16: A/B-frag row16 == C/D col

  __shared__ unsigned short KV[128 * 40];   // union: K[128][40] / Vt[32][132]
  __shared__ unsigned short Pb[4][16 * 40]; // per-wave P chunk (A layout)

  size_t base = ((size_t)b * LL) * CC + (size_t)h * DHH;

  // Q A-frag: a[m=l16][k=quad*8+j], one 16B global read per lane
  int myq = q0 + wid * 16 + l16;
  bf16x8 aQ = {};
  if (myq < rows)
    aQ = *(const bf16x8*)(qh + base + (size_t)myq * CC + quad * 8);

  f32x4 acc[32] = {};
  int nch = (kp + 127) >> 7;  // live 128-key chunks (1..4)

  // ---- phase 1: scores via MFMA ----
#pragma unroll
  for (int c = 0; c < 4; ++c) {
    if (c < nch) {
      int kbase = c << 7;
      __syncthreads();
      for (int idx = t; idx < 1024; idx += 256) {
        int key = idx >> 3, c4 = idx & 7;
        int gk = kbase + key;
        us4 v = {0, 0, 0, 0};
        if (gk < kp) v = *(const us4*)(kh + base + (size_t)gk * CC + c4 * 4);
        *(us4*)&KV[key * 40 + c4 * 4] = v;
      }
      __syncthreads();
#pragma unroll
      for (int tt = 0; tt < 8; ++tt) {
        bf16x8 bK = *(const bf16x8*)&KV[(tt * 16 + l16) * 40 + quad * 8];
        acc[c * 8 + tt] = MFMA16(aQ, bK, acc[c * 8 + tt]);
      }
    }
  }

  // ---- phase 2: softmax in registers ----
  // C layout: query row = quad*4 + r, key = tile*16 + l16
  const float scale = 0.17677669529663687f;  // 1/sqrt(32)
  float mx[4] = {-1e30f, -1e30f, -1e30f, -1e30f};
#pragma unroll
  for (int c = 0; c < 4; ++c) {
    if (c < nch) {
#pragma unroll
      for (int tt = 0; tt < 8; ++tt) {
        int ti = c * 8 + tt;
        float sb = (ti * 16 + l16 < kp) ? 0.f : -1e30f;
#pragma unroll
        for (int r = 0; r < 4; ++r) {
          float v = fmaf(acc[ti][r], scale, sb);
          acc[ti][r] = v;
          mx[r] = fmaxf(mx[r], v);
        }
      }
    }
  }
#pragma unroll
  for (int o = 1; o < 16; o <<= 1)
#pragma unroll
    for (int r = 0; r < 4; ++r) mx[r] = fmaxf(mx[r], __shfl_xor(mx[r], o));
  float sum[4] = {0.f, 0.f, 0.f, 0.f};
#pragma unroll
  for (int c = 0; c < 4; ++c) {
    if (c < nch) {
#pragma unroll
      for (int tt = 0; tt < 8; ++tt) {
        int ti = c * 8 + tt;
#pragma unroll
        for (int r = 0; r < 4; ++r) {
          float p = __expf(acc[ti][r] - mx[r]);
          acc[ti][r] = p;
          sum[r] += p;
        }
      }
    }
  }
#pragma unroll
  for (int o = 1; o < 16; o <<= 1)
#pragma unroll
    for (int r = 0; r < 4; ++r) sum[r] += __shfl_xor(sum[r], o);
  float inv[4];
#pragma unroll
  for (int r = 0; r < 4; ++r) inv[r] = 1.f / sum[r];

  // ---- phase 3: PV via MFMA ----
  f32x4 o0 = {}, o1 = {};
  unsigned short* Pw = Pb[wid];
#pragma unroll
  for (int c = 0; c < 4; ++c) {
    if (c < nch) {
      int kbase = c << 7;
      __syncthreads();
      // stage V^T chunk: Vt[d][key], pitch 132 shorts
      for (int idx = t; idx < 1024; idx += 256) {
        int key = idx >> 3, c4 = idx & 7;
        int gk = kbase + key;
        us4 v = {0, 0, 0, 0};
        if (gk < kp) v = *(const us4*)(vh + base + (size_t)gk * CC + c4 * 4);
#pragma unroll
        for (int j = 0; j < 4; ++j) KV[(c4 * 4 + j) * 132 + key] = v[j];
      }
      __syncthreads();
#pragma unroll
      for (int g = 0; g < 4; ++g) {
        if (kbase + g * 32 < kp) {
          int t0 = c * 8 + g * 2;
          // write P group (32 keys) to wave-private LDS in A layout
#pragma unroll
          for (int tt = 0; tt < 2; ++tt)
#pragma unroll
            for (int r = 0; r < 4; ++r)
              Pw[(quad * 4 + r) * 40 + tt * 16 + l16] =
                  f2bf(acc[t0 + tt][r] * inv[r]);
          __builtin_amdgcn_sched_barrier(0);
          __builtin_amdgcn_s_waitcnt(0xc07f);  // lgkmcnt(0): wave-local fence
          __builtin_amdgcn_sched_barrier(0);
          bf16x8 aP = *(const bf16x8*)&Pw[l16 * 40 + quad * 8];
          int koff = g * 32 + quad * 8;
          struct U8 { us4 a, b; };
          U8 u0, u1;
          u0.a = *(const us4*)&KV[l16 * 132 + koff];
          u0.b = *(const us4*)&KV[l16 * 132 + koff + 4];
          u1.a = *(const us4*)&KV[(16 + l16) * 132 + koff];
          u1.b = *(const us4*)&KV[(16 + l16) * 132 + koff + 4];
          bf16x8 bV0 = __builtin_bit_cast(bf16x8, u0);
          bf16x8 bV1 = __builtin_bit_cast(bf16x8, u1);
          o0 = MFMA16(aP, bV0, o0);
          o1 = MFMA16(aP, bV1, o1);
        }
      }
    }
  }

  // ---- store: C layout row=quad*4+r (query), col=l16 (d) ----
#pragma unroll
  for (int r = 0; r < 4; ++r) {
    int q = q0 + wid * 16 + quad * 4 + r;
    if (q < rows) {
      ah[base + (size_t)q * CC + l16] = f2bf(o0[r]);
      ah[base + (size_t)q * CC + 16 + l16] = f2bf(o1[r]);
    }
  }
}

// ---------------------------------------------------------------------------
// K7: out-proj via bf16 MFMA + scatter + residual + ratio (unchanged).
// ---------------------------------------------------------------------------
__global__ __launch_bounds__(256) void k_outproj(
    const unsigned short* __restrict__ ah, const int* __restrict__ codes,
    const unsigned short* __restrict__ Wouth, const float* __restrict__ bout,
    const float* __restrict__ x, const float* __restrict__ ratio,
    float* __restrict__ out, unsigned short* __restrict__ outh) {
  int b = blockIdx.y;
  int l0 = blockIdx.x * 32;
  int t = threadIdx.x;
  __shared__ unsigned short A1[32][264];
  __shared__ int cd[32];
  if (t < 32) cd[t] = codes[b * LL + l0 + t];
  __syncthreads();
  for (int idx = t; idx < 32 * 64; idx += 256) {
    int r = idx >> 6, c4 = idx & 63;
    int c = cd[r];
    us4 v = {0, 0, 0, 0};
    if (c >= 0) v = ((const us4*)(ah + ((size_t)b * LL + c) * CC))[c4];
    *(us4*)&A1[r][c4 * 4] = v;
  }
  __syncthreads();
  int lane = t & 63, wid = t >> 6, quad = lane >> 4, row16 = lane & 15;
  f32x4 acc[2][4] = {};
  for (int k0 = 0; k0 < CC; k0 += 32) {
    bf16x8 a0 = *(const bf16x8*)&A1[row16][k0 + quad * 8];
    bf16x8 a1 = *(const bf16x8*)&A1[16 + row16][k0 + quad * 8];
#pragma unroll
    for (int nt = 0; nt < 4; ++nt) {
      int n = wid * 64 + nt * 16 + row16;
      bf16x8 bfr = *(const bf16x8*)&Wouth[(size_t)n * CC + k0 + quad * 8];
      acc[0][nt] = MFMA16(a0, bfr, acc[0][nt]);
      acc[1][nt] = MFMA16(a1, bfr, acc[1][nt]);
    }
  }
  float rt_ratio = ratio[b];
#pragma unroll
  for (int rt = 0; rt < 2; ++rt) {
#pragma unroll
    for (int nt = 0; nt < 4; ++nt) {
      int n = wid * 64 + nt * 16 + row16;
      float bias = bout[n];
#pragma unroll
      for (int r = 0; r < 4; ++r) {
        int rl = rt * 16 + quad * 4 + r;
        int c = cd[rl];
        float y = (c >= 0) ? (acc[rt][nt][r] + bias) : 0.f;
        size_t o = ((size_t)b * LL + l0 + rl) * CC + n;
        float res = (y + x[o]) * rt_ratio;
        out[o] = res;
        outh[o] = f2bf(res);
      }
    }
  }
}

// ---------------------------------------------------------------------------
// K8: fused MLP via bf16 MFMA (unchanged).
// ---------------------------------------------------------------------------
__global__ __launch_bounds__(256) void k_mlp(
    const unsigned short* __restrict__ outh,
    const unsigned short* __restrict__ Wm1h, const float* __restrict__ bm1,
    const unsigned short* __restrict__ Wm2h, const float* __restrict__ bm2,
    float* __restrict__ out) {
  __shared__ unsigned short A1[32][264];
  __shared__ unsigned short Hs[32][520];
  int t = threadIdx.x;
  int tok0 = blockIdx.x * 32;
  for (int idx = t; idx < 32 * 64; idx += 256) {
    int r = idx >> 6, c4 = idx & 63;
    *(us4*)&A1[r][c4 * 4] =
        ((const us4*)(outh + (size_t)(tok0 + r) * CC))[c4];
  }
  __syncthreads();
  int lane = t & 63, wid = t >> 6, quad = lane >> 4, row16 = lane & 15;

  f32x4 acc1[2][8] = {};
  for (int k0 = 0; k0 < CC; k0 += 32) {
    bf16x8 a0 = *(const bf16x8*)&A1[row16][k0 + quad * 8];
    bf16x8 a1 = *(const bf16x8*)&A1[16 + row16][k0 + quad * 8];
#pragma unroll
    for (int nt = 0; nt < 8; ++nt) {
      int n = wid * 128 + nt * 16 + row16;
      bf16x8 bfr = *(const bf16x8*)&Wm1h[(size_t)n * CC + k0 + quad * 8];
      acc1[0][nt] = MFMA16(a0, bfr, acc1[0][nt]);
      acc1[1][nt] = MFMA16(a1, bfr, acc1[1][nt]);
    }
  }
#pragma unroll
  for (int rt = 0; rt < 2; ++rt) {
#pragma unroll
    for (int nt = 0; nt < 8; ++nt) {
      int n = wid * 128 + nt * 16 + row16;
      float bias = bm1[n];
#pragma unroll
      for (int r = 0; r < 4; ++r) {
        float v = fmaxf(acc1[rt][nt][r] + bias, 0.f);
        Hs[rt * 16 + quad * 4 + r][n] = f2bf(v);
      }
    }
  }
  __syncthreads();

  f32x4 acc2[2][4] = {};
  for (int k0 = 0; k0 < 2 * CC; k0 += 32) {
    bf16x8 a0 = *(const bf16x8*)&Hs[row16][k0 + quad * 8];
    bf16x8 a1 = *(const bf16x8*)&Hs[16 + row16][k0 + quad * 8];
#pragma unroll
    for (int nt = 0; nt < 4; ++nt) {
      int n = wid * 64 + nt * 16 + row16;
      bf16x8 bfr = *(const bf16x8*)&Wm2h[(size_t)n * (2 * CC) + k0 + quad * 8];
      acc2[0][nt] = MFMA16(a0, bfr, acc2[0][nt]);
      acc2[1][nt] = MFMA16(a1, bfr, acc2[1][nt]);
    }
  }
#pragma unroll
  for (int rt = 0; rt < 2; ++rt) {
#pragma unroll
    for (int nt = 0; nt < 4; ++nt) {
      int n = wid * 64 + nt * 16 + row16;
      float bias = bm2[n];
#pragma unroll
      for (int r = 0; r < 4; ++r) {
        size_t o = (size_t)(tok0 + rt * 16 + quad * 4 + r) * CC + n;
        out[o] = out[o] + acc2[rt][nt][r] + bias;
      }
    }
  }
}

// ---------------------------------------------------------------------------
extern "C" void kernel_launch(void* const* d_in, const int* in_sizes, int n_in,
                              void* d_out, int out_size, void* d_ws,
                              size_t ws_size, hipStream_t stream) {
  (void)in_sizes; (void)n_in; (void)out_size; (void)ws_size;
  const float* x     = (const float*)d_in[0];
  const float* ratio = (const float*)d_in[3];
  const float* gum   = (const float*)d_in[4];
  const float* Ws1   = (const float*)d_in[5];
  const float* bs1   = (const float*)d_in[6];
  const float* Ws2   = (const float*)d_in[7];
  const float* bs2   = (const float*)d_in[8];
  const float* Win   = (const float*)d_in[9];
  const float* b_in  = (const float*)d_in[10];
  const float* Wout  = (const float*)d_in[11];
  const float* bout  = (const float*)d_in[12];
  const float* Wm1   = (const float*)d_in[13];
  const float* bm1   = (const float*)d_in[14];
  const float* Wm2   = (const float*)d_in[15];
  const float* bm2   = (const float*)d_in[16];
  float* out = (float*)d_out;

  // workspace layout
  const size_t NXC = (size_t)NN * CC;  // 8388608
  float* z    = (float*)d_ws;                     // N f32
  int* k_per  = (int*)(z + NN);                   // 128 ints
  int* k_maxp = k_per + 64;
  int* codes  = k_per + 128;                      // N ints
  int* row2l  = codes + NN;                       // N ints
  unsigned short* xh    = (unsigned short*)(row2l + NN);  // N*C bf16
  unsigned short* qh    = xh + NXC;
  unsigned short* kh    = qh + NXC;
  unsigned short* vh    = kh + NXC;
  unsigned short* ahb   = vh + NXC;
  unsigned short* outh  = ahb + NXC;
  unsigned short* Winh  = outh + NXC;             // 196608
  unsigned short* Wouth = Winh + 3 * CC * CC;     // 65536
  unsigned short* Wm1h  = Wouth + CC * CC;        // 131072
  unsigned short* Wm2h  = Wm1h + 2 * CC * CC;     // 131072

  k_f2bf<<<(int)((NXC + 255) / 256), 256, 0, stream>>>(x, xh, (int)NXC);
  k_f2bf<<<(3 * CC * CC + 255) / 256, 256, 0, stream>>>(Win, Winh, 3 * CC * CC);
  k_f2bf<<<(CC * CC + 255) / 256, 256, 0, stream>>>(Wout, Wouth, CC * CC);
  k_f2bf<<<(2 * CC * CC + 255) / 256, 256, 0, stream>>>(Wm1, Wm1h, 2 * CC * CC);
  k_f2bf<<<(2 * CC * CC + 255) / 256, 256, 0, stream>>>(Wm2, Wm2h, 2 * CC * CC);

  k_scorer<<<NN / 8, 256, 0, stream>>>(x, Ws1, bs1, Ws2, bs2, z);
  k_kper<<<1, 64, 0, stream>>>(ratio, k_per, k_maxp);
  k_lsg<<<BB, 256, 0, stream>>>(z, gum);
  k_select<<<BB, 512, 0, stream>>>(z, k_per, k_maxp, codes, row2l);
  k_qkv<<<dim3(16, BB), 256, 0, stream>>>(xh, row2l, k_per, Winh, b_in, qh, kh, vh);
  k_attn<<<dim3(8, HH, BB), 256, 0, stream>>>(qh, kh, vh, k_per, ahb);
  k_outproj<<<dim3(16, BB), 256, 0, stream>>>(ahb, codes, Wouth, bout, x, ratio, out, outh);
  k_mlp<<<NN / 32, 256, 0, stream>>>(outh, Wm1h, bm1, Wm2h, bm2, out);
}

// Round 5
// 464.016 us; speedup vs baseline: 8.5475x; 1.5202x over previous
//
#include <hip/hip_runtime.h>
#include <hip/hip_bf16.h>
#include <math.h>

// Problem constants (from reference)
#define BB 64
#define LL 512
#define CC 256
#define HH 8
#define DHH 32
#define NN (BB * LL)

typedef __attribute__((ext_vector_type(8))) short bf16x8;   // MFMA A/B frag
typedef __attribute__((ext_vector_type(4))) float f32x4;    // MFMA C/D frag
typedef __attribute__((ext_vector_type(4))) unsigned short us4;

#define MFMA16(a, b, c) __builtin_amdgcn_mfma_f32_16x16x32_bf16(a, b, c, 0, 0, 0)

__device__ __forceinline__ unsigned short f2bf(float f) {
  unsigned u = __builtin_bit_cast(unsigned, f);
  u += 0x7fffu + ((u >> 16) & 1u);  // RNE
  return (unsigned short)(u >> 16);
}
__device__ __forceinline__ float bf2f(unsigned short h) {
  unsigned u = ((unsigned)h) << 16;
  return __builtin_bit_cast(float, u);
}

// ---------------------------------------------------------------------------
// K0: fused conversions — x->bf16; Ws1->hi+lo bf16; Win/Wout/Wm1/Wm2->bf16.
// ---------------------------------------------------------------------------
__global__ __launch_bounds__(256) void k_cvt(
    const float* __restrict__ x, unsigned short* __restrict__ xh,
    const float* __restrict__ Ws1, unsigned short* __restrict__ W1h,
    unsigned short* __restrict__ W1l, const float* __restrict__ Win,
    unsigned short* __restrict__ Winh, const float* __restrict__ Wout,
    unsigned short* __restrict__ Wouth, const float* __restrict__ Wm1,
    unsigned short* __restrict__ Wm1h, const float* __restrict__ Wm2,
    unsigned short* __restrict__ Wm2h) {
  const int NX = NN * CC;
  const int NW1 = CC * CC;
  const int NWIN = 3 * CC * CC;
  const int NWM = 2 * CC * CC;
  int i = blockIdx.x * 256 + threadIdx.x;
  if (i < NX) { xh[i] = f2bf(x[i]); return; }
  i -= NX;
  if (i < NW1) {
    float v = Ws1[i];
    unsigned short hb = f2bf(v);
    W1h[i] = hb;
    W1l[i] = f2bf(v - bf2f(hb));
    return;
  }
  i -= NW1;
  if (i < NWIN) { Winh[i] = f2bf(Win[i]); return; }
  i -= NWIN;
  if (i < NW1) { Wouth[i] = f2bf(Wout[i]); return; }
  i -= NW1;
  if (i < NWM) { Wm1h[i] = f2bf(Wm1[i]); return; }
  i -= NWM;
  if (i < NWM) Wm2h[i] = f2bf(Wm2[i]);
}

// ---------------------------------------------------------------------------
// K1 v2: scorer via split-bf16 MFMA (3-term: xh@Wh + xh@Wl + xl@Wh, fp32
// accumulate -> ~1e-5 rel error, far below gumbel rank gaps). Block = 32
// tokens, 4 waves; wave owns 64 hidden cols. x hi/lo computed in-kernel.
// Epilogue: relu(+bs1)*Ws2[n], butterfly-sum over 16 lanes, LDS cross-wave.
// ---------------------------------------------------------------------------
__global__ __launch_bounds__(256) void k_scorer(
    const float* __restrict__ x, const unsigned short* __restrict__ W1h,
    const unsigned short* __restrict__ W1l, const float* __restrict__ bs1,
    const float* __restrict__ Ws2, const float* __restrict__ bs2,
    float* __restrict__ scores) {
  __shared__ unsigned short Ah[32][264];
  __shared__ unsigned short Al[32][264];
  __shared__ float red[4][32];
  int t = threadIdx.x;
  int tok0 = blockIdx.x * 32;
  for (int idx = t; idx < 32 * 64; idx += 256) {
    int r = idx >> 6, c4 = idx & 63;
    float4 v = *(const float4*)(x + (size_t)(tok0 + r) * CC + c4 * 4);
    float vv[4] = {v.x, v.y, v.z, v.w};
    unsigned short hb[4], lb[4];
#pragma unroll
    for (int j = 0; j < 4; ++j) {
      hb[j] = f2bf(vv[j]);
      lb[j] = f2bf(vv[j] - bf2f(hb[j]));
    }
    *(us4*)&Ah[r][c4 * 4] = *(us4*)hb;
    *(us4*)&Al[r][c4 * 4] = *(us4*)lb;
  }
  __syncthreads();
  int lane = t & 63, wid = t >> 6, quad = lane >> 4, l16 = lane & 15;
  f32x4 acc[2][4] = {};
  for (int k0 = 0; k0 < CC; k0 += 32) {
    bf16x8 a0h = *(const bf16x8*)&Ah[l16][k0 + quad * 8];
    bf16x8 a1h = *(const bf16x8*)&Ah[16 + l16][k0 + quad * 8];
    bf16x8 a0l = *(const bf16x8*)&Al[l16][k0 + quad * 8];
    bf16x8 a1l = *(const bf16x8*)&Al[16 + l16][k0 + quad * 8];
#pragma unroll
    for (int nt = 0; nt < 4; ++nt) {
      int n = wid * 64 + nt * 16 + l16;
      bf16x8 bh = *(const bf16x8*)&W1h[(size_t)n * CC + k0 + quad * 8];
      bf16x8 bl = *(const bf16x8*)&W1l[(size_t)n * CC + k0 + quad * 8];
      acc[0][nt] = MFMA16(a0h, bh, acc[0][nt]);
      acc[0][nt] = MFMA16(a0h, bl, acc[0][nt]);
      acc[0][nt] = MFMA16(a0l, bh, acc[0][nt]);
      acc[1][nt] = MFMA16(a1h, bh, acc[1][nt]);
      acc[1][nt] = MFMA16(a1h, bl, acc[1][nt]);
      acc[1][nt] = MFMA16(a1l, bh, acc[1][nt]);
    }
  }
  float rs[2][4] = {};
#pragma unroll
  for (int nt = 0; nt < 4; ++nt) {
    int n = wid * 64 + nt * 16 + l16;
    float b1 = bs1[n], w2 = Ws2[n];
#pragma unroll
    for (int rt = 0; rt < 2; ++rt)
#pragma unroll
      for (int r = 0; r < 4; ++r)
        rs[rt][r] += fmaxf(acc[rt][nt][r] + b1, 0.f) * w2;
  }
#pragma unroll
  for (int o = 1; o < 16; o <<= 1)
#pragma unroll
    for (int rt = 0; rt < 2; ++rt)
#pragma unroll
      for (int r = 0; r < 4; ++r) rs[rt][r] += __shfl_xor(rs[rt][r], o);
  if (l16 == 0) {
#pragma unroll
    for (int rt = 0; rt < 2; ++rt)
#pragma unroll
      for (int r = 0; r < 4; ++r)
        red[wid][rt * 16 + quad * 4 + r] = rs[rt][r];
  }
  __syncthreads();
  if (t < 32)
    scores[tok0 + t] = red[0][t] + red[1][t] + red[2][t] + red[3][t] + bs2[0];
}

// ---------------------------------------------------------------------------
// K2a: k_per / k_max
// ---------------------------------------------------------------------------
__global__ __launch_bounds__(64) void k_kper(const float* __restrict__ ratio,
                                             int* __restrict__ k_per,
                                             int* __restrict__ k_maxp) {
  int t = threadIdx.x;
  int kp = (int)ceilf(ratio[t] * (float)LL);
  kp = min(max(kp, 1), LL);
  k_per[t] = kp;
  int m = kp;
  for (int o = 32; o > 0; o >>= 1) m = max(m, __shfl_down(m, o));
  if (t == 0) *k_maxp = m;
}

// ---------------------------------------------------------------------------
// K2: z = log_softmax(scores) + gumbel (in place, fp32)
// ---------------------------------------------------------------------------
__global__ __launch_bounds__(256) void k_lsg(float* __restrict__ z,
                                             const float* __restrict__ gumbel) {
  int b = blockIdx.x, t = threadIdx.x;
  int lane = t & 63, wid = t >> 6;
  __shared__ float wred[4];
  float v0 = z[b * LL + t], v1 = z[b * LL + 256 + t];
  float m = fmaxf(v0, v1);
  for (int o = 32; o > 0; o >>= 1) m = fmaxf(m, __shfl_down(m, o));
  if (lane == 0) wred[wid] = m;
  __syncthreads();
  m = fmaxf(fmaxf(wred[0], wred[1]), fmaxf(wred[2], wred[3]));
  __syncthreads();
  float e = expf(v0 - m) + expf(v1 - m);
  for (int o = 32; o > 0; o >>= 1) e += __shfl_down(e, o);
  if (lane == 0) wred[wid] = e;
  __syncthreads();
  float lse = m + logf(wred[0] + wred[1] + wred[2] + wred[3]);
  z[b * LL + t] = v0 - lse + gumbel[b * LL + t];
  z[b * LL + 256 + t] = v1 - lse + gumbel[b * LL + 256 + t];
}

// ---------------------------------------------------------------------------
// K3: selection (fp32, unchanged)
// ---------------------------------------------------------------------------
__global__ __launch_bounds__(512) void k_select(
    const float* __restrict__ z, const int* __restrict__ k_per,
    const int* __restrict__ k_maxp, int* __restrict__ codes,
    int* __restrict__ row2l) {
  __shared__ float zs[LL];
  __shared__ int sel[LL];
  int b = blockIdx.x, l = threadIdx.x;
  int kp = k_per[b], km = *k_maxp;
  float zl = z[b * LL + l];
  zs[l] = zl;
  __syncthreads();
  int rank = 0;
  for (int j = 0; j < LL; ++j) {
    float zj = zs[j];
    rank += (zj > zl) || (zj == zl && j < l);
  }
  int s = (rank < km) ? 1 : 0;
  sel[l] = s;
  __syncthreads();
  int ps = 0;
  for (int j = 0; j < l; ++j) ps += sel[j];
  int kept = s && (ps < kp);
  int keptPrefix = min(ps, kp);
  int code;
  if (kept)
    code = ps;
  else if ((l - keptPrefix) < (km - kp))
    code = kp;
  else
    code = -1;
  codes[b * LL + l] = code;
  if (kept) row2l[b * LL + ps] = l;
}

// ---------------------------------------------------------------------------
// K4: qkv in-proj via bf16 MFMA (unchanged).
// ---------------------------------------------------------------------------
__global__ __launch_bounds__(256) void k_qkv(
    const unsigned short* __restrict__ xh, const int* __restrict__ row2l,
    const int* __restrict__ k_per, const unsigned short* __restrict__ Winh,
    const float* __restrict__ b_in, unsigned short* __restrict__ qh,
    unsigned short* __restrict__ kh, unsigned short* __restrict__ vh) {
  int b = blockIdx.y;
  int kp = k_per[b];
  int rows = (kp < LL) ? kp + 1 : LL;
  int r0 = blockIdx.x * 32;
  if (r0 >= rows) return;
  __shared__ unsigned short A1[32][264];
  int t = threadIdx.x;
  for (int idx = t; idx < 32 * 64; idx += 256) {
    int r = idx >> 6, c4 = idx & 63;
    int gr = r0 + r;
    us4 v = {0, 0, 0, 0};
    if (gr < kp) {
      int l = row2l[b * LL + gr];
      v = ((const us4*)(xh + ((size_t)b * LL + l) * CC))[c4];
    }
    *(us4*)&A1[r][c4 * 4] = v;
  }
  __syncthreads();
  int lane = t & 63, wid = t >> 6, quad = lane >> 4, row16 = lane & 15;
  f32x4 acc[2][12] = {};
  for (int k0 = 0; k0 < CC; k0 += 32) {
    bf16x8 a0 = *(const bf16x8*)&A1[row16][k0 + quad * 8];
    bf16x8 a1 = *(const bf16x8*)&A1[16 + row16][k0 + quad * 8];
#pragma unroll
    for (int nt = 0; nt < 12; ++nt) {
      int n = wid * 192 + nt * 16 + row16;
      bf16x8 bfr = *(const bf16x8*)&Winh[(size_t)n * CC + k0 + quad * 8];
      acc[0][nt] = MFMA16(a0, bfr, acc[0][nt]);
      acc[1][nt] = MFMA16(a1, bfr, acc[1][nt]);
    }
  }
#pragma unroll
  for (int rt = 0; rt < 2; ++rt) {
#pragma unroll
    for (int nt = 0; nt < 12; ++nt) {
      int n = wid * 192 + nt * 16 + row16;  // 0..767
      int which = n >> 8, nc = n & 255;
      unsigned short* dst = (which == 0) ? qh : (which == 1) ? kh : vh;
      float bias = b_in[n];
#pragma unroll
      for (int r = 0; r < 4; ++r) {
        int row = r0 + rt * 16 + quad * 4 + r;
        if (row < rows)
          dst[((size_t)b * LL + row) * CC + nc] = f2bf(acc[rt][nt][r] + bias);
      }
    }
  }
}

// ---------------------------------------------------------------------------
// K6 v4: online-softmax flash attention via MFMA. Block = (64 q, head, b),
// 4 waves x 16 queries. Per 128-key chunk: stage K[128][40] + V^T[32][132]
// (one sync pair), 8 score MFMAs, online m/l update (single __expf), batched
// P->LDS round-trip (wave-private [16][132], in-wave DS ordering, no manual
// fences), 4x2 PV MFMAs. 2 syncs/chunk. LDS ~45.8 KB -> 3 blocks/CU.
// ---------------------------------------------------------------------------
__global__ __launch_bounds__(256) void k_attn(
    const unsigned short* __restrict__ qh, const unsigned short* __restrict__ kh,
    const unsigned short* __restrict__ vh, const int* __restrict__ k_per,
    unsigned short* __restrict__ ah) {
  int h = blockIdx.y, b = blockIdx.z;
  int kp = k_per[b];
  int rows = (kp < LL) ? kp + 1 : LL;
  int q0 = blockIdx.x * 64;
  if (q0 >= rows) return;
  int t = threadIdx.x;
  int lane = t & 63, wid = t >> 6, quad = lane >> 4, l16 = lane & 15;

  __shared__ unsigned short Kc[128 * 40];
  __shared__ unsigned short Vt[32 * 132];
  __shared__ unsigned short Pb[4][16 * 132];

  size_t base = ((size_t)b * LL) * CC + (size_t)h * DHH;

  int myq = q0 + wid * 16 + l16;
  bf16x8 aQ = {};
  if (myq < rows)
    aQ = *(const bf16x8*)(qh + base + (size_t)myq * CC + quad * 8);

  const float scale = 0.17677669529663687f;  // 1/sqrt(32)
  float m[4], l[4];
  f32x4 o0 = {}, o1 = {};
#pragma unroll
  for (int r = 0; r < 4; ++r) { m[r] = -1e30f; l[r] = 0.f; }

  int nch = (kp + 127) >> 7;
  unsigned short* Pw = Pb[wid];

  for (int c = 0; c < nch; ++c) {
    int kbase = c << 7;
    __syncthreads();  // guard Kc/Vt overwrite vs previous chunk's reads
    for (int idx = t; idx < 1024; idx += 256) {
      int key = idx >> 3, c4 = idx & 7;
      int gk = kbase + key;
      us4 kv = {0, 0, 0, 0}, vv = {0, 0, 0, 0};
      if (gk < kp) {
        kv = *(const us4*)(kh + base + (size_t)gk * CC + c4 * 4);
        vv = *(const us4*)(vh + base + (size_t)gk * CC + c4 * 4);
      }
      *(us4*)&Kc[key * 40 + c4 * 4] = kv;
#pragma unroll
      for (int j = 0; j < 4; ++j) Vt[(c4 * 4 + j) * 132 + key] = vv[j];
    }
    __syncthreads();
    // scores for this chunk (8 tiles of 16 keys)
    f32x4 s[8];
#pragma unroll
    for (int tt = 0; tt < 8; ++tt) {
      f32x4 z4 = {};
      bf16x8 bK = *(const bf16x8*)&Kc[(tt * 16 + l16) * 40 + quad * 8];
      s[tt] = MFMA16(aQ, bK, z4);
    }
    // online softmax update (C layout: row=quad*4+r, key=tt*16+l16)
    float cm[4] = {-1e30f, -1e30f, -1e30f, -1e30f};
#pragma unroll
    for (int tt = 0; tt < 8; ++tt) {
      float sb = (kbase + tt * 16 + l16 < kp) ? 0.f : -1e30f;
#pragma unroll
      for (int r = 0; r < 4; ++r) {
        float v = fmaf(s[tt][r], scale, sb);
        s[tt][r] = v;
        cm[r] = fmaxf(cm[r], v);
      }
    }
#pragma unroll
    for (int o = 1; o < 16; o <<= 1)
#pragma unroll
      for (int r = 0; r < 4; ++r) cm[r] = fmaxf(cm[r], __shfl_xor(cm[r], o));
    float alpha[4], cs[4] = {0.f, 0.f, 0.f, 0.f};
#pragma unroll
    for (int r = 0; r < 4; ++r) {
      float mn = fmaxf(m[r], cm[r]);
      alpha[r] = __expf(m[r] - mn);
      m[r] = mn;
    }
#pragma unroll
    for (int tt = 0; tt < 8; ++tt)
#pragma unroll
      for (int r = 0; r < 4; ++r) {
        float p = __expf(s[tt][r] - m[r]);
        s[tt][r] = p;
        cs[r] += p;
      }
#pragma unroll
    for (int o = 1; o < 16; o <<= 1)
#pragma unroll
      for (int r = 0; r < 4; ++r) cs[r] += __shfl_xor(cs[r], o);
#pragma unroll
    for (int r = 0; r < 4; ++r) {
      l[r] = l[r] * alpha[r] + cs[r];
      o0[r] *= alpha[r];
      o1[r] *= alpha[r];
    }
    // batched P write (wave-private; in-wave DS ordering makes reads safe)
#pragma unroll
    for (int tt = 0; tt < 8; ++tt)
#pragma unroll
      for (int r = 0; r < 4; ++r)
        Pw[(quad * 4 + r) * 132 + tt * 16 + l16] = f2bf(s[tt][r]);
    // PV: 4 groups of 32 keys
#pragma unroll
    for (int g = 0; g < 4; ++g) {
      if (kbase + g * 32 < kp) {
        bf16x8 aP = *(const bf16x8*)&Pw[l16 * 132 + g * 32 + quad * 8];
        int koff = g * 32 + quad * 8;
        struct U8 { us4 a, b; };
        U8 u0, u1;
        u0.a = *(const us4*)&Vt[l16 * 132 + koff];
        u0.b = *(const us4*)&Vt[l16 * 132 + koff + 4];
        u1.a = *(const us4*)&Vt[(16 + l16) * 132 + koff];
        u1.b = *(const us4*)&Vt[(16 + l16) * 132 + koff + 4];
        o0 = MFMA16(aP, __builtin_bit_cast(bf16x8, u0), o0);
        o1 = MFMA16(aP, __builtin_bit_cast(bf16x8, u1), o1);
      }
    }
  }
#pragma unroll
  for (int r = 0; r < 4; ++r) {
    int q = q0 + wid * 16 + quad * 4 + r;
    if (q < rows) {
      float invl = 1.f / l[r];
      ah[base + (size_t)q * CC + l16] = f2bf(o0[r] * invl);
      ah[base + (size_t)q * CC + 16 + l16] = f2bf(o1[r] * invl);
    }
  }
}

// ---------------------------------------------------------------------------
// K7: out-proj via bf16 MFMA + scatter + residual + ratio (unchanged).
// ---------------------------------------------------------------------------
__global__ __launch_bounds__(256) void k_outproj(
    const unsigned short* __restrict__ ah, const int* __restrict__ codes,
    const unsigned short* __restrict__ Wouth, const float* __restrict__ bout,
    const float* __restrict__ x, const float* __restrict__ ratio,
    float* __restrict__ out, unsigned short* __restrict__ outh) {
  int b = blockIdx.y;
  int l0 = blockIdx.x * 32;
  int t = threadIdx.x;
  __shared__ unsigned short A1[32][264];
  __shared__ int cd[32];
  if (t < 32) cd[t] = codes[b * LL + l0 + t];
  __syncthreads();
  for (int idx = t; idx < 32 * 64; idx += 256) {
    int r = idx >> 6, c4 = idx & 63;
    int c = cd[r];
    us4 v = {0, 0, 0, 0};
    if (c >= 0) v = ((const us4*)(ah + ((size_t)b * LL + c) * CC))[c4];
    *(us4*)&A1[r][c4 * 4] = v;
  }
  __syncthreads();
  int lane = t & 63, wid = t >> 6, quad = lane >> 4, row16 = lane & 15;
  f32x4 acc[2][4] = {};
  for (int k0 = 0; k0 < CC; k0 += 32) {
    bf16x8 a0 = *(const bf16x8*)&A1[row16][k0 + quad * 8];
    bf16x8 a1 = *(const bf16x8*)&A1[16 + row16][k0 + quad * 8];
#pragma unroll
    for (int nt = 0; nt < 4; ++nt) {
      int n = wid * 64 + nt * 16 + row16;
      bf16x8 bfr = *(const bf16x8*)&Wouth[(size_t)n * CC + k0 + quad * 8];
      acc[0][nt] = MFMA16(a0, bfr, acc[0][nt]);
      acc[1][nt] = MFMA16(a1, bfr, acc[1][nt]);
    }
  }
  float rt_ratio = ratio[b];
#pragma unroll
  for (int rt = 0; rt < 2; ++rt) {
#pragma unroll
    for (int nt = 0; nt < 4; ++nt) {
      int n = wid * 64 + nt * 16 + row16;
      float bias = bout[n];
#pragma unroll
      for (int r = 0; r < 4; ++r) {
        int rl = rt * 16 + quad * 4 + r;
        int c = cd[rl];
        float y = (c >= 0) ? (acc[rt][nt][r] + bias) : 0.f;
        size_t o = ((size_t)b * LL + l0 + rl) * CC + n;
        float res = (y + x[o]) * rt_ratio;
        out[o] = res;
        outh[o] = f2bf(res);
      }
    }
  }
}

// ---------------------------------------------------------------------------
// K8: fused MLP via bf16 MFMA (unchanged).
// ---------------------------------------------------------------------------
__global__ __launch_bounds__(256) void k_mlp(
    const unsigned short* __restrict__ outh,
    const unsigned short* __restrict__ Wm1h, const float* __restrict__ bm1,
    const unsigned short* __restrict__ Wm2h, const float* __restrict__ bm2,
    float* __restrict__ out) {
  __shared__ unsigned short A1[32][264];
  __shared__ unsigned short Hs[32][520];
  int t = threadIdx.x;
  int tok0 = blockIdx.x * 32;
  for (int idx = t; idx < 32 * 64; idx += 256) {
    int r = idx >> 6, c4 = idx & 63;
    *(us4*)&A1[r][c4 * 4] =
        ((const us4*)(outh + (size_t)(tok0 + r) * CC))[c4];
  }
  __syncthreads();
  int lane = t & 63, wid = t >> 6, quad = lane >> 4, row16 = lane & 15;

  f32x4 acc1[2][8] = {};
  for (int k0 = 0; k0 < CC; k0 += 32) {
    bf16x8 a0 = *(const bf16x8*)&A1[row16][k0 + quad * 8];
    bf16x8 a1 = *(const bf16x8*)&A1[16 + row16][k0 + quad * 8];
#pragma unroll
    for (int nt = 0; nt < 8; ++nt) {
      int n = wid * 128 + nt * 16 + row16;
      bf16x8 bfr = *(const bf16x8*)&Wm1h[(size_t)n * CC + k0 + quad * 8];
      acc1[0][nt] = MFMA16(a0, bfr, acc1[0][nt]);
      acc1[1][nt] = MFMA16(a1, bfr, acc1[1][nt]);
    }
  }
#pragma unroll
  for (int rt = 0; rt < 2; ++rt) {
#pragma unroll
    for (int nt = 0; nt < 8; ++nt) {
      int n = wid * 128 + nt * 16 + row16;
      float bias = bm1[n];
#pragma unroll
      for (int r = 0; r < 4; ++r) {
        float v = fmaxf(acc1[rt][nt][r] + bias, 0.f);
        Hs[rt * 16 + quad * 4 + r][n] = f2bf(v);
      }
    }
  }
  __syncthreads();

  f32x4 acc2[2][4] = {};
  for (int k0 = 0; k0 < 2 * CC; k0 += 32) {
    bf16x8 a0 = *(const bf16x8*)&Hs[row16][k0 + quad * 8];
    bf16x8 a1 = *(const bf16x8*)&Hs[16 + row16][k0 + quad * 8];
#pragma unroll
    for (int nt = 0; nt < 4; ++nt) {
      int n = wid * 64 + nt * 16 + row16;
      bf16x8 bfr = *(const bf16x8*)&Wm2h[(size_t)n * (2 * CC) + k0 + quad * 8];
      acc2[0][nt] = MFMA16(a0, bfr, acc2[0][nt]);
      acc2[1][nt] = MFMA16(a1, bfr, acc2[1][nt]);
    }
  }
#pragma unroll
  for (int rt = 0; rt < 2; ++rt) {
#pragma unroll
    for (int nt = 0; nt < 4; ++nt) {
      int n = wid * 64 + nt * 16 + row16;
      float bias = bm2[n];
#pragma unroll
      for (int r = 0; r < 4; ++r) {
        size_t o = (size_t)(tok0 + rt * 16 + quad * 4 + r) * CC + n;
        out[o] = out[o] + acc2[rt][nt][r] + bias;
      }
    }
  }
}

// ---------------------------------------------------------------------------
extern "C" void kernel_launch(void* const* d_in, const int* in_sizes, int n_in,
                              void* d_out, int out_size, void* d_ws,
                              size_t ws_size, hipStream_t stream) {
  (void)in_sizes; (void)n_in; (void)out_size; (void)ws_size;
  const float* x     = (const float*)d_in[0];
  const float* ratio = (const float*)d_in[3];
  const float* gum   = (const float*)d_in[4];
  const float* Ws1   = (const float*)d_in[5];
  const float* bs1   = (const float*)d_in[6];
  const float* Ws2   = (const float*)d_in[7];
  const float* bs2   = (const float*)d_in[8];
  const float* Win   = (const float*)d_in[9];
  const float* b_in  = (const float*)d_in[10];
  const float* Wout  = (const float*)d_in[11];
  const float* bout  = (const float*)d_in[12];
  const float* Wm1   = (const float*)d_in[13];
  const float* bm1   = (const float*)d_in[14];
  const float* Wm2   = (const float*)d_in[15];
  const float* bm2   = (const float*)d_in[16];
  float* out = (float*)d_out;

  // workspace layout
  const size_t NXC = (size_t)NN * CC;  // 8388608
  float* z    = (float*)d_ws;                     // N f32
  int* k_per  = (int*)(z + NN);                   // 128 ints
  int* k_maxp = k_per + 64;
  int* codes  = k_per + 128;                      // N ints
  int* row2l  = codes + NN;                       // N ints
  unsigned short* xh    = (unsigned short*)(row2l + NN);  // N*C bf16
  unsigned short* qh    = xh + NXC;
  unsigned short* kh    = qh + NXC;
  unsigned short* vh    = kh + NXC;
  unsigned short* ahb   = vh + NXC;
  unsigned short* outh  = ahb + NXC;
  unsigned short* Winh  = outh + NXC;             // 196608
  unsigned short* Wouth = Winh + 3 * CC * CC;     // 65536
  unsigned short* Wm1h  = Wouth + CC * CC;        // 131072
  unsigned short* Wm2h  = Wm1h + 2 * CC * CC;     // 131072
  unsigned short* W1h   = Wm2h + 2 * CC * CC;     // 65536
  unsigned short* W1l   = W1h + CC * CC;          // 65536

  const int cvt_total = NN * CC + CC * CC + 3 * CC * CC + CC * CC +
                        2 * CC * CC + 2 * CC * CC;
  k_cvt<<<(cvt_total + 255) / 256, 256, 0, stream>>>(
      x, xh, Ws1, W1h, W1l, Win, Winh, Wout, Wouth, Wm1, Wm1h, Wm2, Wm2h);

  k_scorer<<<NN / 32, 256, 0, stream>>>(x, W1h, W1l, bs1, Ws2, bs2, z);
  k_kper<<<1, 64, 0, stream>>>(ratio, k_per, k_maxp);
  k_lsg<<<BB, 256, 0, stream>>>(z, gum);
  k_select<<<BB, 512, 0, stream>>>(z, k_per, k_maxp, codes, row2l);
  k_qkv<<<dim3(16, BB), 256, 0, stream>>>(xh, row2l, k_per, Winh, b_in, qh, kh, vh);
  k_attn<<<dim3(8, HH, BB), 256, 0, stream>>>(qh, kh, vh, k_per, ahb);
  k_outproj<<<dim3(16, BB), 256, 0, stream>>>(ahb, codes, Wouth, bout, x, ratio, out, outh);
  k_mlp<<<NN / 32, 256, 0, stream>>>(outh, Wm1h, bm1, Wm2h, bm2, out);
}

// Round 6
// 426.168 us; speedup vs baseline: 9.3067x; 1.0888x over previous
//
#include <hip/hip_runtime.h>
#include <hip/hip_bf16.h>
#include <math.h>

// Problem constants (from reference)
#define BB 64
#define LL 512
#define CC 256
#define HH 8
#define DHH 32
#define NN (BB * LL)

typedef __attribute__((ext_vector_type(8))) short bf16x8;   // MFMA A/B frag
typedef __attribute__((ext_vector_type(4))) float f32x4;    // MFMA C/D frag
typedef __attribute__((ext_vector_type(4))) unsigned short us4;

#define MFMA16(a, b, c) __builtin_amdgcn_mfma_f32_16x16x32_bf16(a, b, c, 0, 0, 0)

__device__ __forceinline__ unsigned short f2bf(float f) {
  unsigned u = __builtin_bit_cast(unsigned, f);
  u += 0x7fffu + ((u >> 16) & 1u);  // RNE
  return (unsigned short)(u >> 16);
}
__device__ __forceinline__ float bf2f(unsigned short h) {
  unsigned u = ((unsigned)h) << 16;
  return __builtin_bit_cast(float, u);
}

// ---------------------------------------------------------------------------
// K0: fused conversions — x->bf16; Ws1->hi+lo bf16; Win/Wout/Wm1/Wm2->bf16.
// ---------------------------------------------------------------------------
__global__ __launch_bounds__(256) void k_cvt(
    const float* __restrict__ x, unsigned short* __restrict__ xh,
    const float* __restrict__ Ws1, unsigned short* __restrict__ W1h,
    unsigned short* __restrict__ W1l, const float* __restrict__ Win,
    unsigned short* __restrict__ Winh, const float* __restrict__ Wout,
    unsigned short* __restrict__ Wouth, const float* __restrict__ Wm1,
    unsigned short* __restrict__ Wm1h, const float* __restrict__ Wm2,
    unsigned short* __restrict__ Wm2h) {
  const int NX = NN * CC;
  const int NW1 = CC * CC;
  const int NWIN = 3 * CC * CC;
  const int NWM = 2 * CC * CC;
  int i = blockIdx.x * 256 + threadIdx.x;
  if (i < NX) { xh[i] = f2bf(x[i]); return; }
  i -= NX;
  if (i < NW1) {
    float v = Ws1[i];
    unsigned short hb = f2bf(v);
    W1h[i] = hb;
    W1l[i] = f2bf(v - bf2f(hb));
    return;
  }
  i -= NW1;
  if (i < NWIN) { Winh[i] = f2bf(Win[i]); return; }
  i -= NWIN;
  if (i < NW1) { Wouth[i] = f2bf(Wout[i]); return; }
  i -= NW1;
  if (i < NWM) { Wm1h[i] = f2bf(Wm1[i]); return; }
  i -= NWM;
  if (i < NWM) Wm2h[i] = f2bf(Wm2[i]);
}

// ---------------------------------------------------------------------------
// K1: scorer via split-bf16 MFMA (unchanged from R4).
// ---------------------------------------------------------------------------
__global__ __launch_bounds__(256) void k_scorer(
    const float* __restrict__ x, const unsigned short* __restrict__ W1h,
    const unsigned short* __restrict__ W1l, const float* __restrict__ bs1,
    const float* __restrict__ Ws2, const float* __restrict__ bs2,
    float* __restrict__ scores) {
  __shared__ unsigned short Ah[32][264];
  __shared__ unsigned short Al[32][264];
  __shared__ float red[4][32];
  int t = threadIdx.x;
  int tok0 = blockIdx.x * 32;
  for (int idx = t; idx < 32 * 64; idx += 256) {
    int r = idx >> 6, c4 = idx & 63;
    float4 v = *(const float4*)(x + (size_t)(tok0 + r) * CC + c4 * 4);
    float vv[4] = {v.x, v.y, v.z, v.w};
    unsigned short hb[4], lb[4];
#pragma unroll
    for (int j = 0; j < 4; ++j) {
      hb[j] = f2bf(vv[j]);
      lb[j] = f2bf(vv[j] - bf2f(hb[j]));
    }
    *(us4*)&Ah[r][c4 * 4] = *(us4*)hb;
    *(us4*)&Al[r][c4 * 4] = *(us4*)lb;
  }
  __syncthreads();
  int lane = t & 63, wid = t >> 6, quad = lane >> 4, l16 = lane & 15;
  f32x4 acc[2][4] = {};
  for (int k0 = 0; k0 < CC; k0 += 32) {
    bf16x8 a0h = *(const bf16x8*)&Ah[l16][k0 + quad * 8];
    bf16x8 a1h = *(const bf16x8*)&Ah[16 + l16][k0 + quad * 8];
    bf16x8 a0l = *(const bf16x8*)&Al[l16][k0 + quad * 8];
    bf16x8 a1l = *(const bf16x8*)&Al[16 + l16][k0 + quad * 8];
#pragma unroll
    for (int nt = 0; nt < 4; ++nt) {
      int n = wid * 64 + nt * 16 + l16;
      bf16x8 bh = *(const bf16x8*)&W1h[(size_t)n * CC + k0 + quad * 8];
      bf16x8 bl = *(const bf16x8*)&W1l[(size_t)n * CC + k0 + quad * 8];
      acc[0][nt] = MFMA16(a0h, bh, acc[0][nt]);
      acc[0][nt] = MFMA16(a0h, bl, acc[0][nt]);
      acc[0][nt] = MFMA16(a0l, bh, acc[0][nt]);
      acc[1][nt] = MFMA16(a1h, bh, acc[1][nt]);
      acc[1][nt] = MFMA16(a1h, bl, acc[1][nt]);
      acc[1][nt] = MFMA16(a1l, bh, acc[1][nt]);
    }
  }
  float rs[2][4] = {};
#pragma unroll
  for (int nt = 0; nt < 4; ++nt) {
    int n = wid * 64 + nt * 16 + l16;
    float b1 = bs1[n], w2 = Ws2[n];
#pragma unroll
    for (int rt = 0; rt < 2; ++rt)
#pragma unroll
      for (int r = 0; r < 4; ++r)
        rs[rt][r] += fmaxf(acc[rt][nt][r] + b1, 0.f) * w2;
  }
#pragma unroll
  for (int o = 1; o < 16; o <<= 1)
#pragma unroll
    for (int rt = 0; rt < 2; ++rt)
#pragma unroll
      for (int r = 0; r < 4; ++r) rs[rt][r] += __shfl_xor(rs[rt][r], o);
  if (l16 == 0) {
#pragma unroll
    for (int rt = 0; rt < 2; ++rt)
#pragma unroll
      for (int r = 0; r < 4; ++r)
        red[wid][rt * 16 + quad * 4 + r] = rs[rt][r];
  }
  __syncthreads();
  if (t < 32)
    scores[tok0 + t] = red[0][t] + red[1][t] + red[2][t] + red[3][t] + bs2[0];
}

// ---------------------------------------------------------------------------
// K2a: k_per / k_max
// ---------------------------------------------------------------------------
__global__ __launch_bounds__(64) void k_kper(const float* __restrict__ ratio,
                                             int* __restrict__ k_per,
                                             int* __restrict__ k_maxp) {
  int t = threadIdx.x;
  int kp = (int)ceilf(ratio[t] * (float)LL);
  kp = min(max(kp, 1), LL);
  k_per[t] = kp;
  int m = kp;
  for (int o = 32; o > 0; o >>= 1) m = max(m, __shfl_down(m, o));
  if (t == 0) *k_maxp = m;
}

// ---------------------------------------------------------------------------
// K2: z = log_softmax(scores) + gumbel (in place, fp32)
// ---------------------------------------------------------------------------
__global__ __launch_bounds__(256) void k_lsg(float* __restrict__ z,
                                             const float* __restrict__ gumbel) {
  int b = blockIdx.x, t = threadIdx.x;
  int lane = t & 63, wid = t >> 6;
  __shared__ float wred[4];
  float v0 = z[b * LL + t], v1 = z[b * LL + 256 + t];
  float m = fmaxf(v0, v1);
  for (int o = 32; o > 0; o >>= 1) m = fmaxf(m, __shfl_down(m, o));
  if (lane == 0) wred[wid] = m;
  __syncthreads();
  m = fmaxf(fmaxf(wred[0], wred[1]), fmaxf(wred[2], wred[3]));
  __syncthreads();
  float e = expf(v0 - m) + expf(v1 - m);
  for (int o = 32; o > 0; o >>= 1) e += __shfl_down(e, o);
  if (lane == 0) wred[wid] = e;
  __syncthreads();
  float lse = m + logf(wred[0] + wred[1] + wred[2] + wred[3]);
  z[b * LL + t] = v0 - lse + gumbel[b * LL + t];
  z[b * LL + 256 + t] = v1 - lse + gumbel[b * LL + 256 + t];
}

// ---------------------------------------------------------------------------
// K3: selection (fp32, unchanged)
// ---------------------------------------------------------------------------
__global__ __launch_bounds__(512) void k_select(
    const float* __restrict__ z, const int* __restrict__ k_per,
    const int* __restrict__ k_maxp, int* __restrict__ codes,
    int* __restrict__ row2l) {
  __shared__ float zs[LL];
  __shared__ int sel[LL];
  int b = blockIdx.x, l = threadIdx.x;
  int kp = k_per[b], km = *k_maxp;
  float zl = z[b * LL + l];
  zs[l] = zl;
  __syncthreads();
  int rank = 0;
  for (int j = 0; j < LL; ++j) {
    float zj = zs[j];
    rank += (zj > zl) || (zj == zl && j < l);
  }
  int s = (rank < km) ? 1 : 0;
  sel[l] = s;
  __syncthreads();
  int ps = 0;
  for (int j = 0; j < l; ++j) ps += sel[j];
  int kept = s && (ps < kp);
  int keptPrefix = min(ps, kp);
  int code;
  if (kept)
    code = ps;
  else if ((l - keptPrefix) < (km - kp))
    code = kp;
  else
    code = -1;
  codes[b * LL + l] = code;
  if (kept) row2l[b * LL + ps] = l;
}

// ---------------------------------------------------------------------------
// K4: qkv in-proj via bf16 MFMA (unchanged).
// ---------------------------------------------------------------------------
__global__ __launch_bounds__(256) void k_qkv(
    const unsigned short* __restrict__ xh, const int* __restrict__ row2l,
    const int* __restrict__ k_per, const unsigned short* __restrict__ Winh,
    const float* __restrict__ b_in, unsigned short* __restrict__ qh,
    unsigned short* __restrict__ kh, unsigned short* __restrict__ vh) {
  int b = blockIdx.y;
  int kp = k_per[b];
  int rows = (kp < LL) ? kp + 1 : LL;
  int r0 = blockIdx.x * 32;
  if (r0 >= rows) return;
  __shared__ unsigned short A1[32][264];
  int t = threadIdx.x;
  for (int idx = t; idx < 32 * 64; idx += 256) {
    int r = idx >> 6, c4 = idx & 63;
    int gr = r0 + r;
    us4 v = {0, 0, 0, 0};
    if (gr < kp) {
      int l = row2l[b * LL + gr];
      v = ((const us4*)(xh + ((size_t)b * LL + l) * CC))[c4];
    }
    *(us4*)&A1[r][c4 * 4] = v;
  }
  __syncthreads();
  int lane = t & 63, wid = t >> 6, quad = lane >> 4, row16 = lane & 15;
  f32x4 acc[2][12] = {};
  for (int k0 = 0; k0 < CC; k0 += 32) {
    bf16x8 a0 = *(const bf16x8*)&A1[row16][k0 + quad * 8];
    bf16x8 a1 = *(const bf16x8*)&A1[16 + row16][k0 + quad * 8];
#pragma unroll
    for (int nt = 0; nt < 12; ++nt) {
      int n = wid * 192 + nt * 16 + row16;
      bf16x8 bfr = *(const bf16x8*)&Winh[(size_t)n * CC + k0 + quad * 8];
      acc[0][nt] = MFMA16(a0, bfr, acc[0][nt]);
      acc[1][nt] = MFMA16(a1, bfr, acc[1][nt]);
    }
  }
#pragma unroll
  for (int rt = 0; rt < 2; ++rt) {
#pragma unroll
    for (int nt = 0; nt < 12; ++nt) {
      int n = wid * 192 + nt * 16 + row16;  // 0..767
      int which = n >> 8, nc = n & 255;
      unsigned short* dst = (which == 0) ? qh : (which == 1) ? kh : vh;
      float bias = b_in[n];
#pragma unroll
      for (int r = 0; r < 4; ++r) {
        int row = r0 + rt * 16 + quad * 4 + r;
        if (row < rows)
          dst[((size_t)b * LL + row) * CC + nc] = f2bf(acc[rt][nt][r] + bias);
      }
    }
  }
}

// ---------------------------------------------------------------------------
// K6: online-softmax flash attention via MFMA (unchanged from R4).
// ---------------------------------------------------------------------------
__global__ __launch_bounds__(256) void k_attn(
    const unsigned short* __restrict__ qh, const unsigned short* __restrict__ kh,
    const unsigned short* __restrict__ vh, const int* __restrict__ k_per,
    unsigned short* __restrict__ ah) {
  int h = blockIdx.y, b = blockIdx.z;
  int kp = k_per[b];
  int rows = (kp < LL) ? kp + 1 : LL;
  int q0 = blockIdx.x * 64;
  if (q0 >= rows) return;
  int t = threadIdx.x;
  int lane = t & 63, wid = t >> 6, quad = lane >> 4, l16 = lane & 15;

  __shared__ unsigned short Kc[128 * 40];
  __shared__ unsigned short Vt[32 * 132];
  __shared__ unsigned short Pb[4][16 * 132];

  size_t base = ((size_t)b * LL) * CC + (size_t)h * DHH;

  int myq = q0 + wid * 16 + l16;
  bf16x8 aQ = {};
  if (myq < rows)
    aQ = *(const bf16x8*)(qh + base + (size_t)myq * CC + quad * 8);

  const float scale = 0.17677669529663687f;  // 1/sqrt(32)
  float m[4], l[4];
  f32x4 o0 = {}, o1 = {};
#pragma unroll
  for (int r = 0; r < 4; ++r) { m[r] = -1e30f; l[r] = 0.f; }

  int nch = (kp + 127) >> 7;
  unsigned short* Pw = Pb[wid];

  for (int c = 0; c < nch; ++c) {
    int kbase = c << 7;
    __syncthreads();  // guard Kc/Vt overwrite vs previous chunk's reads
    for (int idx = t; idx < 1024; idx += 256) {
      int key = idx >> 3, c4 = idx & 7;
      int gk = kbase + key;
      us4 kv = {0, 0, 0, 0}, vv = {0, 0, 0, 0};
      if (gk < kp) {
        kv = *(const us4*)(kh + base + (size_t)gk * CC + c4 * 4);
        vv = *(const us4*)(vh + base + (size_t)gk * CC + c4 * 4);
      }
      *(us4*)&Kc[key * 40 + c4 * 4] = kv;
#pragma unroll
      for (int j = 0; j < 4; ++j) Vt[(c4 * 4 + j) * 132 + key] = vv[j];
    }
    __syncthreads();
    f32x4 s[8];
#pragma unroll
    for (int tt = 0; tt < 8; ++tt) {
      f32x4 z4 = {};
      bf16x8 bK = *(const bf16x8*)&Kc[(tt * 16 + l16) * 40 + quad * 8];
      s[tt] = MFMA16(aQ, bK, z4);
    }
    float cm[4] = {-1e30f, -1e30f, -1e30f, -1e30f};
#pragma unroll
    for (int tt = 0; tt < 8; ++tt) {
      float sb = (kbase + tt * 16 + l16 < kp) ? 0.f : -1e30f;
#pragma unroll
      for (int r = 0; r < 4; ++r) {
        float v = fmaf(s[tt][r], scale, sb);
        s[tt][r] = v;
        cm[r] = fmaxf(cm[r], v);
      }
    }
#pragma unroll
    for (int o = 1; o < 16; o <<= 1)
#pragma unroll
      for (int r = 0; r < 4; ++r) cm[r] = fmaxf(cm[r], __shfl_xor(cm[r], o));
    float alpha[4], cs[4] = {0.f, 0.f, 0.f, 0.f};
#pragma unroll
    for (int r = 0; r < 4; ++r) {
      float mn = fmaxf(m[r], cm[r]);
      alpha[r] = __expf(m[r] - mn);
      m[r] = mn;
    }
#pragma unroll
    for (int tt = 0; tt < 8; ++tt)
#pragma unroll
      for (int r = 0; r < 4; ++r) {
        float p = __expf(s[tt][r] - m[r]);
        s[tt][r] = p;
        cs[r] += p;
      }
#pragma unroll
    for (int o = 1; o < 16; o <<= 1)
#pragma unroll
      for (int r = 0; r < 4; ++r) cs[r] += __shfl_xor(cs[r], o);
#pragma unroll
    for (int r = 0; r < 4; ++r) {
      l[r] = l[r] * alpha[r] + cs[r];
      o0[r] *= alpha[r];
      o1[r] *= alpha[r];
    }
#pragma unroll
    for (int tt = 0; tt < 8; ++tt)
#pragma unroll
      for (int r = 0; r < 4; ++r)
        Pw[(quad * 4 + r) * 132 + tt * 16 + l16] = f2bf(s[tt][r]);
#pragma unroll
    for (int g = 0; g < 4; ++g) {
      if (kbase + g * 32 < kp) {
        bf16x8 aP = *(const bf16x8*)&Pw[l16 * 132 + g * 32 + quad * 8];
        int koff = g * 32 + quad * 8;
        struct U8 { us4 a, b; };
        U8 u0, u1;
        u0.a = *(const us4*)&Vt[l16 * 132 + koff];
        u0.b = *(const us4*)&Vt[l16 * 132 + koff + 4];
        u1.a = *(const us4*)&Vt[(16 + l16) * 132 + koff];
        u1.b = *(const us4*)&Vt[(16 + l16) * 132 + koff + 4];
        o0 = MFMA16(aP, __builtin_bit_cast(bf16x8, u0), o0);
        o1 = MFMA16(aP, __builtin_bit_cast(bf16x8, u1), o1);
      }
    }
  }
#pragma unroll
  for (int r = 0; r < 4; ++r) {
    int q = q0 + wid * 16 + quad * 4 + r;
    if (q < rows) {
      float invl = 1.f / l[r];
      ah[base + (size_t)q * CC + l16] = f2bf(o0[r] * invl);
      ah[base + (size_t)q * CC + 16 + l16] = f2bf(o1[r] * invl);
    }
  }
}

// ---------------------------------------------------------------------------
// K7 v3: FUSED out-proj + scatter + residual + MLP. Block = 32 node
// positions (b, l0), 4 waves. Phase A: gather attn rows -> A1, outproj GEMM,
// res = (y + x)*ratio kept in 32 fp32 regs (C layout == GEMM2 epilogue
// layout). res bf16 overwrites A1 (after sync) as MLP input. Phase B: GEMM1
// split into 2 col-halves (acc 32 regs, keeps VGPR<=128 for 4 waves/EU),
// relu -> Hs bf16; GEMM2; out = res + delta, written ONCE. No intermediate
// global traffic. LDS ~50.3 KB -> 3 blocks/CU.
// ---------------------------------------------------------------------------
__global__ __launch_bounds__(256, 4) void k_opmlp(
    const unsigned short* __restrict__ ah, const int* __restrict__ codes,
    const unsigned short* __restrict__ Wouth, const float* __restrict__ bout,
    const float* __restrict__ x, const float* __restrict__ ratio,
    const unsigned short* __restrict__ Wm1h, const float* __restrict__ bm1,
    const unsigned short* __restrict__ Wm2h, const float* __restrict__ bm2,
    float* __restrict__ out) {
  int b = blockIdx.y;
  int l0 = blockIdx.x * 32;
  int t = threadIdx.x;
  __shared__ unsigned short A1[32][264];
  __shared__ unsigned short Hs[32][520];
  __shared__ int cd[32];
  if (t < 32) cd[t] = codes[b * LL + l0 + t];
  __syncthreads();
  for (int idx = t; idx < 32 * 64; idx += 256) {
    int r = idx >> 6, c4 = idx & 63;
    int c = cd[r];
    us4 v = {0, 0, 0, 0};
    if (c >= 0) v = ((const us4*)(ah + ((size_t)b * LL + c) * CC))[c4];
    *(us4*)&A1[r][c4 * 4] = v;
  }
  __syncthreads();
  int lane = t & 63, wid = t >> 6, quad = lane >> 4, l16 = lane & 15;

  // ---- phase A: out-proj GEMM (wave owns cols wid*64..+63) ----
  f32x4 acc[2][4] = {};
  for (int k0 = 0; k0 < CC; k0 += 32) {
    bf16x8 a0 = *(const bf16x8*)&A1[l16][k0 + quad * 8];
    bf16x8 a1 = *(const bf16x8*)&A1[16 + l16][k0 + quad * 8];
#pragma unroll
    for (int nt = 0; nt < 4; ++nt) {
      int n = wid * 64 + nt * 16 + l16;
      bf16x8 bfr = *(const bf16x8*)&Wouth[(size_t)n * CC + k0 + quad * 8];
      acc[0][nt] = MFMA16(a0, bfr, acc[0][nt]);
      acc[1][nt] = MFMA16(a1, bfr, acc[1][nt]);
    }
  }
  // epilogue: res in registers (layout matches GEMM2 epilogue exactly)
  float res[2][4][4];
  float rt_ratio = ratio[b];
#pragma unroll
  for (int rt = 0; rt < 2; ++rt) {
#pragma unroll
    for (int nt = 0; nt < 4; ++nt) {
      int n = wid * 64 + nt * 16 + l16;
      float bias = bout[n];
#pragma unroll
      for (int r = 0; r < 4; ++r) {
        int rl = rt * 16 + quad * 4 + r;
        int c = cd[rl];
        float y = (c >= 0) ? (acc[rt][nt][r] + bias) : 0.f;
        size_t o = ((size_t)b * LL + l0 + rl) * CC + n;
        res[rt][nt][r] = (y + x[o]) * rt_ratio;
      }
    }
  }
  __syncthreads();  // all A1 reads done -> safe to overwrite
#pragma unroll
  for (int rt = 0; rt < 2; ++rt)
#pragma unroll
    for (int nt = 0; nt < 4; ++nt) {
      int n = wid * 64 + nt * 16 + l16;
#pragma unroll
      for (int r = 0; r < 4; ++r)
        A1[rt * 16 + quad * 4 + r][n] = f2bf(res[rt][nt][r]);
    }
  __syncthreads();

  // ---- phase B: MLP GEMM1 (2 col-halves of 64 each, acc stays 32 regs) ----
#pragma unroll
  for (int half = 0; half < 2; ++half) {
    f32x4 acc1[2][4] = {};
    for (int k0 = 0; k0 < CC; k0 += 32) {
      bf16x8 a0 = *(const bf16x8*)&A1[l16][k0 + quad * 8];
      bf16x8 a1 = *(const bf16x8*)&A1[16 + l16][k0 + quad * 8];
#pragma unroll
      for (int nt = 0; nt < 4; ++nt) {
        int n = wid * 128 + half * 64 + nt * 16 + l16;
        bf16x8 bfr = *(const bf16x8*)&Wm1h[(size_t)n * CC + k0 + quad * 8];
        acc1[0][nt] = MFMA16(a0, bfr, acc1[0][nt]);
        acc1[1][nt] = MFMA16(a1, bfr, acc1[1][nt]);
      }
    }
#pragma unroll
    for (int rt = 0; rt < 2; ++rt)
#pragma unroll
      for (int nt = 0; nt < 4; ++nt) {
        int n = wid * 128 + half * 64 + nt * 16 + l16;
        float bias = bm1[n];
#pragma unroll
        for (int r = 0; r < 4; ++r) {
          float v = fmaxf(acc1[rt][nt][r] + bias, 0.f);
          Hs[rt * 16 + quad * 4 + r][n] = f2bf(v);
        }
      }
  }
  __syncthreads();

  // ---- GEMM2: delta = Hs @ Wm2^T; out = res + delta + bm2 ----
  f32x4 acc2[2][4] = {};
  for (int k0 = 0; k0 < 2 * CC; k0 += 32) {
    bf16x8 a0 = *(const bf16x8*)&Hs[l16][k0 + quad * 8];
    bf16x8 a1 = *(const bf16x8*)&Hs[16 + l16][k0 + quad * 8];
#pragma unroll
    for (int nt = 0; nt < 4; ++nt) {
      int n = wid * 64 + nt * 16 + l16;
      bf16x8 bfr = *(const bf16x8*)&Wm2h[(size_t)n * (2 * CC) + k0 + quad * 8];
      acc2[0][nt] = MFMA16(a0, bfr, acc2[0][nt]);
      acc2[1][nt] = MFMA16(a1, bfr, acc2[1][nt]);
    }
  }
#pragma unroll
  for (int rt = 0; rt < 2; ++rt) {
#pragma unroll
    for (int nt = 0; nt < 4; ++nt) {
      int n = wid * 64 + nt * 16 + l16;
      float bias = bm2[n];
#pragma unroll
      for (int r = 0; r < 4; ++r) {
        int rl = rt * 16 + quad * 4 + r;
        size_t o = ((size_t)b * LL + l0 + rl) * CC + n;
        out[o] = res[rt][nt][r] + acc2[rt][nt][r] + bias;
      }
    }
  }
}

// ---------------------------------------------------------------------------
extern "C" void kernel_launch(void* const* d_in, const int* in_sizes, int n_in,
                              void* d_out, int out_size, void* d_ws,
                              size_t ws_size, hipStream_t stream) {
  (void)in_sizes; (void)n_in; (void)out_size; (void)ws_size;
  const float* x     = (const float*)d_in[0];
  const float* ratio = (const float*)d_in[3];
  const float* gum   = (const float*)d_in[4];
  const float* Ws1   = (const float*)d_in[5];
  const float* bs1   = (const float*)d_in[6];
  const float* Ws2   = (const float*)d_in[7];
  const float* bs2   = (const float*)d_in[8];
  const float* Win   = (const float*)d_in[9];
  const float* b_in  = (const float*)d_in[10];
  const float* Wout  = (const float*)d_in[11];
  const float* bout  = (const float*)d_in[12];
  const float* Wm1   = (const float*)d_in[13];
  const float* bm1   = (const float*)d_in[14];
  const float* Wm2   = (const float*)d_in[15];
  const float* bm2   = (const float*)d_in[16];
  float* out = (float*)d_out;

  // workspace layout
  const size_t NXC = (size_t)NN * CC;  // 8388608
  float* z    = (float*)d_ws;                     // N f32
  int* k_per  = (int*)(z + NN);                   // 128 ints
  int* k_maxp = k_per + 64;
  int* codes  = k_per + 128;                      // N ints
  int* row2l  = codes + NN;                       // N ints
  unsigned short* xh    = (unsigned short*)(row2l + NN);  // N*C bf16
  unsigned short* qh    = xh + NXC;
  unsigned short* kh    = qh + NXC;
  unsigned short* vh    = kh + NXC;
  unsigned short* ahb   = vh + NXC;
  unsigned short* Winh  = ahb + NXC;              // 196608
  unsigned short* Wouth = Winh + 3 * CC * CC;     // 65536
  unsigned short* Wm1h  = Wouth + CC * CC;        // 131072
  unsigned short* Wm2h  = Wm1h + 2 * CC * CC;     // 131072
  unsigned short* W1h   = Wm2h + 2 * CC * CC;     // 65536
  unsigned short* W1l   = W1h + CC * CC;          // 65536

  const int cvt_total = NN * CC + CC * CC + 3 * CC * CC + CC * CC +
                        2 * CC * CC + 2 * CC * CC;
  k_cvt<<<(cvt_total + 255) / 256, 256, 0, stream>>>(
      x, xh, Ws1, W1h, W1l, Win, Winh, Wout, Wouth, Wm1, Wm1h, Wm2, Wm2h);

  k_scorer<<<NN / 32, 256, 0, stream>>>(x, W1h, W1l, bs1, Ws2, bs2, z);
  k_kper<<<1, 64, 0, stream>>>(ratio, k_per, k_maxp);
  k_lsg<<<BB, 256, 0, stream>>>(z, gum);
  k_select<<<BB, 512, 0, stream>>>(z, k_per, k_maxp, codes, row2l);
  k_qkv<<<dim3(16, BB), 256, 0, stream>>>(xh, row2l, k_per, Winh, b_in, qh, kh, vh);
  k_attn<<<dim3(8, HH, BB), 256, 0, stream>>>(qh, kh, vh, k_per, ahb);
  k_opmlp<<<dim3(16, BB), 256, 0, stream>>>(ahb, codes, Wouth, bout, x, ratio,
                                            Wm1h, bm1, Wm2h, bm2, out);
}

// Round 7
// 399.623 us; speedup vs baseline: 9.9249x; 1.0664x over previous
//
#include <hip/hip_runtime.h>
#include <hip/hip_bf16.h>
#include <math.h>

// Problem constants (from reference)
#define BB 64
#define LL 512
#define CC 256
#define HH 8
#define DHH 32
#define NN (BB * LL)

typedef __attribute__((ext_vector_type(8))) short bf16x8;   // MFMA A/B frag
typedef __attribute__((ext_vector_type(4))) float f32x4;    // MFMA C/D frag
typedef __attribute__((ext_vector_type(4))) unsigned short us4;

#define MFMA16(a, b, c) __builtin_amdgcn_mfma_f32_16x16x32_bf16(a, b, c, 0, 0, 0)

__device__ __forceinline__ unsigned short f2bf(float f) {
  unsigned u = __builtin_bit_cast(unsigned, f);
  u += 0x7fffu + ((u >> 16) & 1u);  // RNE
  return (unsigned short)(u >> 16);
}
__device__ __forceinline__ float bf2f(unsigned short h) {
  unsigned u = ((unsigned)h) << 16;
  return __builtin_bit_cast(float, u);
}

// ---------------------------------------------------------------------------
// K0 v2: weight-only conversions (x->bf16 moved into k_scorer).
// ---------------------------------------------------------------------------
__global__ __launch_bounds__(256) void k_cvt(
    const float* __restrict__ Ws1, unsigned short* __restrict__ W1h,
    unsigned short* __restrict__ W1l, const float* __restrict__ Win,
    unsigned short* __restrict__ Winh, const float* __restrict__ Wout,
    unsigned short* __restrict__ Wouth, const float* __restrict__ Wm1,
    unsigned short* __restrict__ Wm1h, const float* __restrict__ Wm2,
    unsigned short* __restrict__ Wm2h) {
  const int NW1 = CC * CC;
  const int NWIN = 3 * CC * CC;
  const int NWM = 2 * CC * CC;
  int i = blockIdx.x * 256 + threadIdx.x;
  if (i < NW1) {
    float v = Ws1[i];
    unsigned short hb = f2bf(v);
    W1h[i] = hb;
    W1l[i] = f2bf(v - bf2f(hb));
    return;
  }
  i -= NW1;
  if (i < NWIN) { Winh[i] = f2bf(Win[i]); return; }
  i -= NWIN;
  if (i < NW1) { Wouth[i] = f2bf(Wout[i]); return; }
  i -= NW1;
  if (i < NWM) { Wm1h[i] = f2bf(Wm1[i]); return; }
  i -= NWM;
  if (i < NWM) Wm2h[i] = f2bf(Wm2[i]);
}

// ---------------------------------------------------------------------------
// K1 v3: scorer via split-bf16 MFMA; also emits xh (bf16 x) as a side
// effect of its hi/lo staging (kills the x pass in k_cvt).
// ---------------------------------------------------------------------------
__global__ __launch_bounds__(256) void k_scorer(
    const float* __restrict__ x, unsigned short* __restrict__ xh,
    const unsigned short* __restrict__ W1h,
    const unsigned short* __restrict__ W1l, const float* __restrict__ bs1,
    const float* __restrict__ Ws2, const float* __restrict__ bs2,
    float* __restrict__ scores) {
  __shared__ unsigned short Ah[32][264];
  __shared__ unsigned short Al[32][264];
  __shared__ float red[4][32];
  int t = threadIdx.x;
  int tok0 = blockIdx.x * 32;
  for (int idx = t; idx < 32 * 64; idx += 256) {
    int r = idx >> 6, c4 = idx & 63;
    float4 v = *(const float4*)(x + (size_t)(tok0 + r) * CC + c4 * 4);
    float vv[4] = {v.x, v.y, v.z, v.w};
    unsigned short hb[4], lb[4];
#pragma unroll
    for (int j = 0; j < 4; ++j) {
      hb[j] = f2bf(vv[j]);
      lb[j] = f2bf(vv[j] - bf2f(hb[j]));
    }
    *(us4*)&Ah[r][c4 * 4] = *(us4*)hb;
    *(us4*)&Al[r][c4 * 4] = *(us4*)lb;
    ((us4*)(xh + (size_t)(tok0 + r) * CC))[c4] = *(us4*)hb;  // side output
  }
  __syncthreads();
  int lane = t & 63, wid = t >> 6, quad = lane >> 4, l16 = lane & 15;
  f32x4 acc[2][4] = {};
  for (int k0 = 0; k0 < CC; k0 += 32) {
    bf16x8 a0h = *(const bf16x8*)&Ah[l16][k0 + quad * 8];
    bf16x8 a1h = *(const bf16x8*)&Ah[16 + l16][k0 + quad * 8];
    bf16x8 a0l = *(const bf16x8*)&Al[l16][k0 + quad * 8];
    bf16x8 a1l = *(const bf16x8*)&Al[16 + l16][k0 + quad * 8];
#pragma unroll
    for (int nt = 0; nt < 4; ++nt) {
      int n = wid * 64 + nt * 16 + l16;
      bf16x8 bh = *(const bf16x8*)&W1h[(size_t)n * CC + k0 + quad * 8];
      bf16x8 bl = *(const bf16x8*)&W1l[(size_t)n * CC + k0 + quad * 8];
      acc[0][nt] = MFMA16(a0h, bh, acc[0][nt]);
      acc[0][nt] = MFMA16(a0h, bl, acc[0][nt]);
      acc[0][nt] = MFMA16(a0l, bh, acc[0][nt]);
      acc[1][nt] = MFMA16(a1h, bh, acc[1][nt]);
      acc[1][nt] = MFMA16(a1h, bl, acc[1][nt]);
      acc[1][nt] = MFMA16(a1l, bh, acc[1][nt]);
    }
  }
  float rs[2][4] = {};
#pragma unroll
  for (int nt = 0; nt < 4; ++nt) {
    int n = wid * 64 + nt * 16 + l16;
    float b1 = bs1[n], w2 = Ws2[n];
#pragma unroll
    for (int rt = 0; rt < 2; ++rt)
#pragma unroll
      for (int r = 0; r < 4; ++r)
        rs[rt][r] += fmaxf(acc[rt][nt][r] + b1, 0.f) * w2;
  }
#pragma unroll
  for (int o = 1; o < 16; o <<= 1)
#pragma unroll
    for (int rt = 0; rt < 2; ++rt)
#pragma unroll
      for (int r = 0; r < 4; ++r) rs[rt][r] += __shfl_xor(rs[rt][r], o);
  if (l16 == 0) {
#pragma unroll
    for (int rt = 0; rt < 2; ++rt)
#pragma unroll
      for (int r = 0; r < 4; ++r)
        red[wid][rt * 16 + quad * 4 + r] = rs[rt][r];
  }
  __syncthreads();
  if (t < 32)
    scores[tok0 + t] = red[0][t] + red[1][t] + red[2][t] + red[3][t] + bs2[0];
}

// ---------------------------------------------------------------------------
// K2 v2: fused kper + log_softmax+gumbel + selection. One block per batch,
// 512 threads. z never leaves LDS; k_max recomputed locally per block.
// ---------------------------------------------------------------------------
__global__ __launch_bounds__(512) void k_presel(
    const float* __restrict__ scores, const float* __restrict__ gumbel,
    const float* __restrict__ ratio, int* __restrict__ k_per,
    int* __restrict__ codes, int* __restrict__ row2l) {
  __shared__ float zs[LL];
  __shared__ int sel[LL];
  __shared__ float red[8];
  __shared__ int kps[64];
  int b = blockIdx.x, l = threadIdx.x;
  int lane = l & 63, wid = l >> 6;
  if (l < 64) {
    int kp_ = (int)ceilf(ratio[l] * (float)LL);
    kp_ = min(max(kp_, 1), LL);
    kps[l] = kp_;
    if (l == b) k_per[b] = kp_;
  }
  __syncthreads();
  int kp = kps[b];
  int km = 0;
#pragma unroll
  for (int j = 0; j < 64; ++j) km = max(km, kps[j]);
  // log-softmax + gumbel
  float v = scores[b * LL + l];
  float m = v;
  for (int o = 32; o > 0; o >>= 1) m = fmaxf(m, __shfl_down(m, o));
  if (lane == 0) red[wid] = m;
  __syncthreads();
  m = red[0];
#pragma unroll
  for (int j = 1; j < 8; ++j) m = fmaxf(m, red[j]);
  __syncthreads();
  float e = expf(v - m);
  for (int o = 32; o > 0; o >>= 1) e += __shfl_down(e, o);
  if (lane == 0) red[wid] = e;
  __syncthreads();
  float tot = red[0];
#pragma unroll
  for (int j = 1; j < 8; ++j) tot += red[j];
  float lse = m + logf(tot);
  float zl = v - lse + gumbel[b * LL + l];
  zs[l] = zl;
  __syncthreads();
  // rank + compaction (unchanged semantics)
  int rank = 0;
  for (int j = 0; j < LL; ++j) {
    float zj = zs[j];
    rank += (zj > zl) || (zj == zl && j < l);
  }
  int s = (rank < km) ? 1 : 0;
  sel[l] = s;
  __syncthreads();
  int ps = 0;
  for (int j = 0; j < l; ++j) ps += sel[j];
  int kept = s && (ps < kp);
  int keptPrefix = min(ps, kp);
  int code;
  if (kept)
    code = ps;
  else if ((l - keptPrefix) < (km - kp))
    code = kp;
  else
    code = -1;
  codes[b * LL + l] = code;
  if (kept) row2l[b * LL + ps] = l;
}

// ---------------------------------------------------------------------------
// K4: qkv in-proj via bf16 MFMA (unchanged from R5).
// ---------------------------------------------------------------------------
__global__ __launch_bounds__(256) void k_qkv(
    const unsigned short* __restrict__ xh, const int* __restrict__ row2l,
    const int* __restrict__ k_per, const unsigned short* __restrict__ Winh,
    const float* __restrict__ b_in, unsigned short* __restrict__ qh,
    unsigned short* __restrict__ kh, unsigned short* __restrict__ vh) {
  int b = blockIdx.y;
  int kp = k_per[b];
  int rows = (kp < LL) ? kp + 1 : LL;
  int r0 = blockIdx.x * 32;
  if (r0 >= rows) return;
  __shared__ unsigned short A1[32][264];
  int t = threadIdx.x;
  for (int idx = t; idx < 32 * 64; idx += 256) {
    int r = idx >> 6, c4 = idx & 63;
    int gr = r0 + r;
    us4 v = {0, 0, 0, 0};
    if (gr < kp) {
      int l = row2l[b * LL + gr];
      v = ((const us4*)(xh + ((size_t)b * LL + l) * CC))[c4];
    }
    *(us4*)&A1[r][c4 * 4] = v;
  }
  __syncthreads();
  int lane = t & 63, wid = t >> 6, quad = lane >> 4, row16 = lane & 15;
  f32x4 acc[2][12] = {};
  for (int k0 = 0; k0 < CC; k0 += 32) {
    bf16x8 a0 = *(const bf16x8*)&A1[row16][k0 + quad * 8];
    bf16x8 a1 = *(const bf16x8*)&A1[16 + row16][k0 + quad * 8];
#pragma unroll
    for (int nt = 0; nt < 12; ++nt) {
      int n = wid * 192 + nt * 16 + row16;
      bf16x8 bfr = *(const bf16x8*)&Winh[(size_t)n * CC + k0 + quad * 8];
      acc[0][nt] = MFMA16(a0, bfr, acc[0][nt]);
      acc[1][nt] = MFMA16(a1, bfr, acc[1][nt]);
    }
  }
#pragma unroll
  for (int rt = 0; rt < 2; ++rt) {
#pragma unroll
    for (int nt = 0; nt < 12; ++nt) {
      int n = wid * 192 + nt * 16 + row16;  // 0..767
      int which = n >> 8, nc = n & 255;
      unsigned short* dst = (which == 0) ? qh : (which == 1) ? kh : vh;
      float bias = b_in[n];
#pragma unroll
      for (int r = 0; r < 4; ++r) {
        int row = r0 + rt * 16 + quad * 4 + r;
        if (row < rows)
          dst[((size_t)b * LL + row) * CC + nc] = f2bf(acc[rt][nt][r] + bias);
      }
    }
  }
}

// ---------------------------------------------------------------------------
// K6 v5: flash attention, 128-query blocks (2 q-groups/wave) — halves K/V
// global re-reads and staging/sync count per query. LDS ~35.6 KB.
// ---------------------------------------------------------------------------
__global__ __launch_bounds__(256, 4) void k_attn(
    const unsigned short* __restrict__ qh, const unsigned short* __restrict__ kh,
    const unsigned short* __restrict__ vh, const int* __restrict__ k_per,
    unsigned short* __restrict__ ah) {
  int h = blockIdx.y, b = blockIdx.z;
  int kp = k_per[b];
  int rows = (kp < LL) ? kp + 1 : LL;
  int q0 = blockIdx.x * 128;
  if (q0 >= rows) return;
  int t = threadIdx.x;
  int lane = t & 63, wid = t >> 6, quad = lane >> 4, l16 = lane & 15;

  __shared__ unsigned short Kc[128 * 40];
  __shared__ unsigned short Vt[32 * 132];
  __shared__ unsigned short Pb[4][16 * 132];

  size_t base = ((size_t)b * LL) * CC + (size_t)h * DHH;

  bf16x8 aQ[2] = {};
  float m[2][4], l[2][4];
  f32x4 o0[2] = {}, o1[2] = {};
#pragma unroll
  for (int g = 0; g < 2; ++g) {
    int myq = q0 + wid * 32 + g * 16 + l16;
    if (myq < rows)
      aQ[g] = *(const bf16x8*)(qh + base + (size_t)myq * CC + quad * 8);
#pragma unroll
    for (int r = 0; r < 4; ++r) { m[g][r] = -1e30f; l[g][r] = 0.f; }
  }
  const float scale = 0.17677669529663687f;  // 1/sqrt(32)
  int nch = (kp + 127) >> 7;
  unsigned short* Pw = Pb[wid];

  for (int c = 0; c < nch; ++c) {
    int kbase = c << 7;
    __syncthreads();  // guard Kc/Vt overwrite vs previous chunk's reads
    for (int idx = t; idx < 1024; idx += 256) {
      int key = idx >> 3, c4 = idx & 7;
      int gk = kbase + key;
      us4 kv = {0, 0, 0, 0}, vv = {0, 0, 0, 0};
      if (gk < kp) {
        kv = *(const us4*)(kh + base + (size_t)gk * CC + c4 * 4);
        vv = *(const us4*)(vh + base + (size_t)gk * CC + c4 * 4);
      }
      *(us4*)&Kc[key * 40 + c4 * 4] = kv;
#pragma unroll
      for (int j = 0; j < 4; ++j) Vt[(c4 * 4 + j) * 132 + key] = vv[j];
    }
    __syncthreads();
#pragma unroll
    for (int g = 0; g < 2; ++g) {
      f32x4 s[8];
#pragma unroll
      for (int tt = 0; tt < 8; ++tt) {
        f32x4 z4 = {};
        bf16x8 bK = *(const bf16x8*)&Kc[(tt * 16 + l16) * 40 + quad * 8];
        s[tt] = MFMA16(aQ[g], bK, z4);
      }
      float cm[4] = {-1e30f, -1e30f, -1e30f, -1e30f};
#pragma unroll
      for (int tt = 0; tt < 8; ++tt) {
        float sb = (kbase + tt * 16 + l16 < kp) ? 0.f : -1e30f;
#pragma unroll
        for (int r = 0; r < 4; ++r) {
          float v = fmaf(s[tt][r], scale, sb);
          s[tt][r] = v;
          cm[r] = fmaxf(cm[r], v);
        }
      }
#pragma unroll
      for (int o = 1; o < 16; o <<= 1)
#pragma unroll
        for (int r = 0; r < 4; ++r) cm[r] = fmaxf(cm[r], __shfl_xor(cm[r], o));
      float alpha[4], cs[4] = {0.f, 0.f, 0.f, 0.f};
#pragma unroll
      for (int r = 0; r < 4; ++r) {
        float mn = fmaxf(m[g][r], cm[r]);
        alpha[r] = __expf(m[g][r] - mn);
        m[g][r] = mn;
      }
#pragma unroll
      for (int tt = 0; tt < 8; ++tt)
#pragma unroll
        for (int r = 0; r < 4; ++r) {
          float p = __expf(s[tt][r] - m[g][r]);
          s[tt][r] = p;
          cs[r] += p;
        }
#pragma unroll
      for (int o = 1; o < 16; o <<= 1)
#pragma unroll
        for (int r = 0; r < 4; ++r) cs[r] += __shfl_xor(cs[r], o);
#pragma unroll
      for (int r = 0; r < 4; ++r) {
        l[g][r] = l[g][r] * alpha[r] + cs[r];
        o0[g][r] *= alpha[r];
        o1[g][r] *= alpha[r];
      }
      // P round-trip (wave-private; in-wave DS ordering incl. across g)
#pragma unroll
      for (int tt = 0; tt < 8; ++tt)
#pragma unroll
        for (int r = 0; r < 4; ++r)
          Pw[(quad * 4 + r) * 132 + tt * 16 + l16] = f2bf(s[tt][r]);
#pragma unroll
      for (int gg = 0; gg < 4; ++gg) {
        if (kbase + gg * 32 < kp) {
          bf16x8 aP = *(const bf16x8*)&Pw[l16 * 132 + gg * 32 + quad * 8];
          int koff = gg * 32 + quad * 8;
          struct U8 { us4 a, bq; };
          U8 u0, u1;
          u0.a = *(const us4*)&Vt[l16 * 132 + koff];
          u0.bq = *(const us4*)&Vt[l16 * 132 + koff + 4];
          u1.a = *(const us4*)&Vt[(16 + l16) * 132 + koff];
          u1.bq = *(const us4*)&Vt[(16 + l16) * 132 + koff + 4];
          o0[g] = MFMA16(aP, __builtin_bit_cast(bf16x8, u0), o0[g]);
          o1[g] = MFMA16(aP, __builtin_bit_cast(bf16x8, u1), o1[g]);
        }
      }
    }
  }
#pragma unroll
  for (int g = 0; g < 2; ++g)
#pragma unroll
    for (int r = 0; r < 4; ++r) {
      int q = q0 + wid * 32 + g * 16 + quad * 4 + r;
      if (q < rows) {
        float invl = 1.f / l[g][r];
        ah[base + (size_t)q * CC + l16] = f2bf(o0[g][r] * invl);
        ah[base + (size_t)q * CC + 16 + l16] = f2bf(o1[g][r] * invl);
      }
    }
}

// ---------------------------------------------------------------------------
// K7 v4: fused out-proj + residual + MLP, K-interleaved GEMM1/GEMM2 so Hs is
// [32][264] (LDS ~34 KB -> 4 blocks/CU). Residual x read as bf16 (xh).
// ---------------------------------------------------------------------------
__global__ __launch_bounds__(256, 4) void k_opmlp(
    const unsigned short* __restrict__ ah, const int* __restrict__ codes,
    const unsigned short* __restrict__ Wouth, const float* __restrict__ bout,
    const unsigned short* __restrict__ xh, const float* __restrict__ ratio,
    const unsigned short* __restrict__ Wm1h, const float* __restrict__ bm1,
    const unsigned short* __restrict__ Wm2h, const float* __restrict__ bm2,
    float* __restrict__ out) {
  int b = blockIdx.y;
  int l0 = blockIdx.x * 32;
  int t = threadIdx.x;
  __shared__ unsigned short A1[32][264];
  __shared__ unsigned short Hs[32][264];
  __shared__ int cd[32];
  if (t < 32) cd[t] = codes[b * LL + l0 + t];
  __syncthreads();
  for (int idx = t; idx < 32 * 64; idx += 256) {
    int r = idx >> 6, c4 = idx & 63;
    int c = cd[r];
    us4 v = {0, 0, 0, 0};
    if (c >= 0) v = ((const us4*)(ah + ((size_t)b * LL + c) * CC))[c4];
    *(us4*)&A1[r][c4 * 4] = v;
  }
  __syncthreads();
  int lane = t & 63, wid = t >> 6, quad = lane >> 4, l16 = lane & 15;

  // ---- phase A: out-proj GEMM (wave owns cols wid*64..+63) ----
  f32x4 acc[2][4] = {};
  for (int k0 = 0; k0 < CC; k0 += 32) {
    bf16x8 a0 = *(const bf16x8*)&A1[l16][k0 + quad * 8];
    bf16x8 a1 = *(const bf16x8*)&A1[16 + l16][k0 + quad * 8];
#pragma unroll
    for (int nt = 0; nt < 4; ++nt) {
      int n = wid * 64 + nt * 16 + l16;
      bf16x8 bfr = *(const bf16x8*)&Wouth[(size_t)n * CC + k0 + quad * 8];
      acc[0][nt] = MFMA16(a0, bfr, acc[0][nt]);
      acc[1][nt] = MFMA16(a1, bfr, acc[1][nt]);
    }
  }
  float res[2][4][4];
  float rt_ratio = ratio[b];
#pragma unroll
  for (int rt = 0; rt < 2; ++rt) {
#pragma unroll
    for (int nt = 0; nt < 4; ++nt) {
      int n = wid * 64 + nt * 16 + l16;
      float bias = bout[n];
#pragma unroll
      for (int r = 0; r < 4; ++r) {
        int rl = rt * 16 + quad * 4 + r;
        int c = cd[rl];
        float y = (c >= 0) ? (acc[rt][nt][r] + bias) : 0.f;
        size_t o = ((size_t)b * LL + l0 + rl) * CC + n;
        res[rt][nt][r] = (y + bf2f(xh[o])) * rt_ratio;
      }
    }
  }
  __syncthreads();  // A1 reads done -> safe to overwrite
#pragma unroll
  for (int rt = 0; rt < 2; ++rt)
#pragma unroll
    for (int nt = 0; nt < 4; ++nt) {
      int n = wid * 64 + nt * 16 + l16;
#pragma unroll
      for (int r = 0; r < 4; ++r)
        A1[rt * 16 + quad * 4 + r][n] = f2bf(res[rt][nt][r]);
    }
  __syncthreads();

  // ---- phase B: K-interleaved MLP. half h: GEMM1 cols h*256..+255 -> Hs,
  // then GEMM2 partial over K = h*256..+255. acc2 accumulates across halves.
  f32x4 acc2[2][4] = {};
#pragma unroll
  for (int half = 0; half < 2; ++half) {
    f32x4 acc1[2][4] = {};
    for (int k0 = 0; k0 < CC; k0 += 32) {
      bf16x8 a0 = *(const bf16x8*)&A1[l16][k0 + quad * 8];
      bf16x8 a1 = *(const bf16x8*)&A1[16 + l16][k0 + quad * 8];
#pragma unroll
      for (int nt = 0; nt < 4; ++nt) {
        int nh = half * 256 + wid * 64 + nt * 16 + l16;  // hidden unit
        bf16x8 bfr = *(const bf16x8*)&Wm1h[(size_t)nh * CC + k0 + quad * 8];
        acc1[0][nt] = MFMA16(a0, bfr, acc1[0][nt]);
        acc1[1][nt] = MFMA16(a1, bfr, acc1[1][nt]);
      }
    }
    if (half == 1) __syncthreads();  // GEMM2-half0 readers done before rewrite
#pragma unroll
    for (int rt = 0; rt < 2; ++rt)
#pragma unroll
      for (int nt = 0; nt < 4; ++nt) {
        int nh = half * 256 + wid * 64 + nt * 16 + l16;
        int hc = nh - half * 256;  // col within Hs
        float bias = bm1[nh];
#pragma unroll
        for (int r = 0; r < 4; ++r) {
          float v = fmaxf(acc1[rt][nt][r] + bias, 0.f);
          Hs[rt * 16 + quad * 4 + r][hc] = f2bf(v);
        }
      }
    __syncthreads();
    for (int k0 = 0; k0 < CC; k0 += 32) {
      bf16x8 a0 = *(const bf16x8*)&Hs[l16][k0 + quad * 8];
      bf16x8 a1 = *(const bf16x8*)&Hs[16 + l16][k0 + quad * 8];
#pragma unroll
      for (int nt = 0; nt < 4; ++nt) {
        int n = wid * 64 + nt * 16 + l16;
        bf16x8 bfr =
            *(const bf16x8*)&Wm2h[(size_t)n * (2 * CC) + half * 256 + k0 + quad * 8];
        acc2[0][nt] = MFMA16(a0, bfr, acc2[0][nt]);
        acc2[1][nt] = MFMA16(a1, bfr, acc2[1][nt]);
      }
    }
  }
#pragma unroll
  for (int rt = 0; rt < 2; ++rt) {
#pragma unroll
    for (int nt = 0; nt < 4; ++nt) {
      int n = wid * 64 + nt * 16 + l16;
      float bias = bm2[n];
#pragma unroll
      for (int r = 0; r < 4; ++r) {
        int rl = rt * 16 + quad * 4 + r;
        size_t o = ((size_t)b * LL + l0 + rl) * CC + n;
        out[o] = res[rt][nt][r] + acc2[rt][nt][r] + bias;
      }
    }
  }
}

// ---------------------------------------------------------------------------
extern "C" void kernel_launch(void* const* d_in, const int* in_sizes, int n_in,
                              void* d_out, int out_size, void* d_ws,
                              size_t ws_size, hipStream_t stream) {
  (void)in_sizes; (void)n_in; (void)out_size; (void)ws_size;
  const float* x     = (const float*)d_in[0];
  const float* ratio = (const float*)d_in[3];
  const float* gum   = (const float*)d_in[4];
  const float* Ws1   = (const float*)d_in[5];
  const float* bs1   = (const float*)d_in[6];
  const float* Ws2   = (const float*)d_in[7];
  const float* bs2   = (const float*)d_in[8];
  const float* Win   = (const float*)d_in[9];
  const float* b_in  = (const float*)d_in[10];
  const float* Wout  = (const float*)d_in[11];
  const float* bout  = (const float*)d_in[12];
  const float* Wm1   = (const float*)d_in[13];
  const float* bm1   = (const float*)d_in[14];
  const float* Wm2   = (const float*)d_in[15];
  const float* bm2   = (const float*)d_in[16];
  float* out = (float*)d_out;

  // workspace layout
  const size_t NXC = (size_t)NN * CC;  // 8388608
  float* z    = (float*)d_ws;                     // N f32 (scores)
  int* k_per  = (int*)(z + NN);                   // 128 ints
  int* codes  = k_per + 128;                      // N ints
  int* row2l  = codes + NN;                       // N ints
  unsigned short* xh    = (unsigned short*)(row2l + NN);  // N*C bf16
  unsigned short* qh    = xh + NXC;
  unsigned short* kh    = qh + NXC;
  unsigned short* vh    = kh + NXC;
  unsigned short* ahb   = vh + NXC;
  unsigned short* Winh  = ahb + NXC;              // 196608
  unsigned short* Wouth = Winh + 3 * CC * CC;     // 65536
  unsigned short* Wm1h  = Wouth + CC * CC;        // 131072
  unsigned short* Wm2h  = Wm1h + 2 * CC * CC;     // 131072
  unsigned short* W1h   = Wm2h + 2 * CC * CC;     // 65536
  unsigned short* W1l   = W1h + CC * CC;          // 65536

  const int cvt_total = 9 * CC * CC;  // weights only
  k_cvt<<<(cvt_total + 255) / 256, 256, 0, stream>>>(
      Ws1, W1h, W1l, Win, Winh, Wout, Wouth, Wm1, Wm1h, Wm2, Wm2h);

  k_scorer<<<NN / 32, 256, 0, stream>>>(x, xh, W1h, W1l, bs1, Ws2, bs2, z);
  k_presel<<<BB, 512, 0, stream>>>(z, gum, ratio, k_per, codes, row2l);
  k_qkv<<<dim3(16, BB), 256, 0, stream>>>(xh, row2l, k_per, Winh, b_in, qh, kh, vh);
  k_attn<<<dim3(4, HH, BB), 256, 0, stream>>>(qh, kh, vh, k_per, ahb);
  k_opmlp<<<dim3(16, BB), 256, 0, stream>>>(ahb, codes, Wouth, bout, xh, ratio,
                                            Wm1h, bm1, Wm2h, bm2, out);
}